// Round 8
// baseline (888.677 us; speedup 1.0000x reference)
//
#include <hip/hip_runtime.h>

// Problem constants (fixed-shape problem)
constexpr int N_    = 8;
constexpr int M_    = 50000;
constexpr int FIN_  = 16;
constexpr int FOUT_ = 32;
constexpr int KCH_  = 4;
constexpr int NNZ_  = 800000;
constexpr int SW_   = 16;                   // floats per slice row (= FIN_)
constexpr int SCAN_NB = (M_ + 255) / 256;   // 196 scan blocks
constexpr int MT_   = 2;                    // m-values per thread in k_final
constexpr int MTILES_ = M_ / MT_;           // 25000 m-tiles (exact)
constexpr int CHR_  = 128;                  // rows per spmm ticket
constexpr int NCH_  = (M_ + CHR_ - 1) / CHR_;   // 391 tickets per slice
constexpr int MEGA_BLOCKS_ = 1024;          // 4 blocks/CU, guaranteed resident
constexpr int RPB_  = 64;                   // fallback spmm rows/block
constexpr int RBLK_ = (M_ + RPB_ - 1) / RPB_;

// Slice mapping: col c = f*8+n of X0  ->  slice s = c&7 = n, w = c>>3 = f.
// Term layout T[(s*M + m)*16 + w] == x[n][m][f]  =>  T0 IS the input x.

typedef float f32x4 __attribute__((ext_vector_type(4)));

__device__ __forceinline__ int xcd_id() {
    int v;
    asm volatile("s_getreg_b32 %0, hwreg(HW_REG_XCC_ID)" : "=s"(v));
    return v & 7;
}

// Relaxed grid barrier: __syncthreads drains vmcnt(0) (compiler-emitted before
// s_barrier), then one LLC atomic add + spin. NO device acquire fence -> the
// per-XCD L2 contents (our slice data) are NOT invalidated.
__device__ __forceinline__ void gbar(int* cnt, int nb) {
    __syncthreads();
    if (threadIdx.x == 0) {
        __hip_atomic_fetch_add(cnt, 1, __ATOMIC_RELAXED, __HIP_MEMORY_SCOPE_AGENT);
        int g = 0;
        while (__hip_atomic_load(cnt, __ATOMIC_RELAXED, __HIP_MEMORY_SCOPE_AGENT) < nb) {
            __builtin_amdgcn_s_sleep(2);
            if (++g > (1 << 22)) break;   // degrade to wrong-answer, never hang
        }
    }
    __syncthreads();
    asm volatile("" ::: "memory");
}

// ---------------------------------------------------------------------------
// CSR build
__global__ void k_hist(const int* __restrict__ row, int* __restrict__ cnt) {
    int i = blockIdx.x * blockDim.x + threadIdx.x;
    if (i < NNZ_) atomicAdd(&cnt[row[i]], 1);
}

__global__ void k_blocksum(const int* __restrict__ cnt, int* __restrict__ bsum) {
    __shared__ int s[256];
    int t = threadIdx.x;
    int idx = blockIdx.x * 256 + t;
    s[t] = (idx < M_) ? cnt[idx] : 0;
    __syncthreads();
    for (int off = 128; off > 0; off >>= 1) {
        if (t < off) s[t] += s[t + off];
        __syncthreads();
    }
    if (t == 0) bsum[blockIdx.x] = s[0];
}

__global__ void k_scan_bsum(const int* __restrict__ bsum, int* __restrict__ boff) {
    __shared__ int s[256];
    int t = threadIdx.x;
    int v = (t < SCAN_NB) ? bsum[t] : 0;
    s[t] = v;
    __syncthreads();
    for (int off = 1; off < 256; off <<= 1) {
        int a = (t >= off) ? s[t - off] : 0;
        __syncthreads();
        s[t] += a;
        __syncthreads();
    }
    if (t < SCAN_NB) boff[t] = s[t] - v;   // exclusive
}

__global__ void k_emit(const int* __restrict__ cnt, const int* __restrict__ boff,
                       int* __restrict__ row_ptr, int* __restrict__ row_tmp) {
    __shared__ int s[256];
    int t = threadIdx.x;
    int idx = blockIdx.x * 256 + t;
    int v = (idx < M_) ? cnt[idx] : 0;
    s[t] = v;
    __syncthreads();
    for (int off = 1; off < 256; off <<= 1) {
        int a = (t >= off) ? s[t - off] : 0;
        __syncthreads();
        s[t] += a;
        __syncthreads();
    }
    if (idx < M_) {
        int r = boff[blockIdx.x] + s[t] - v;
        row_ptr[idx] = r;
        row_tmp[idx] = r;
    }
    if (idx == 0) row_ptr[M_] = NNZ_;
}

__global__ void k_scatter(const float* __restrict__ vals, const int* __restrict__ row,
                          const int* __restrict__ col, int* __restrict__ row_tmp,
                          int2* __restrict__ pairs) {
    int i = blockIdx.x * blockDim.x + threadIdx.x;
    if (i >= NNZ_) return;
    int p = atomicAdd(&row_tmp[row[i]], 1);
    pairs[p] = make_int2(__float_as_int(vals[i]), col[i]);
}

// ---------------------------------------------------------------------------
// Fused 3-phase SpMM chain. Each block pins itself to its XCD's slice; data
// written in phase p is gathered from the SAME per-XCD L2 in phase p+1.
// 16 lanes per row: 4 nnz-slots x 4 col-groups; shuffle-reduce over slots.
__global__ __launch_bounds__(256, 4) void k_mega(
        const float* __restrict__ x, const int* __restrict__ rp,
        const long long* __restrict__ pairs,
        float* __restrict__ T1, float* __restrict__ T2, float* __restrict__ T3,
        int* __restrict__ sync) {
    const int s = xcd_id();
    int* tk  = sync;            // [3][8] tickets
    int* bar = sync + 24;       // [2] barriers
    const int nb = (int)gridDim.x;
    __shared__ int sh_ck;

    const int grp  = threadIdx.x >> 4;        // 16 row-groups per block
    const int slot = (threadIdx.x >> 2) & 3;  // nnz slot
    const int cg   = threadIdx.x & 3;         // col group (4 floats)

    for (int p = 0; p < 3; ++p) {
        const float* Xs = (p == 0) ? x : (p == 1) ? T1 : T2;
        const float* PV = (p == 0) ? (const float*)nullptr : (p == 1) ? x : T1;
        float*       Y  = (p == 0) ? T1 : (p == 1) ? T2 : T3;
        const float  scale = (p == 0) ? 1.f : 2.f;
        const float* Xsl = Xs + (size_t)s * M_ * SW_;

        for (;;) {
            __syncthreads();
            if (threadIdx.x == 0)
                sh_ck = __hip_atomic_fetch_add(&tk[p * 8 + s], 1,
                                               __ATOMIC_RELAXED,
                                               __HIP_MEMORY_SCOPE_AGENT);
            __syncthreads();
            const int ck = sh_ck;
            if (ck >= NCH_) break;
            int r = ck * CHR_ + grp;
#pragma unroll 1
            for (int i = 0; i < CHR_ / 16; ++i, r += 16) {
                if (r >= M_) break;
                const int jb = rp[r], je = rp[r + 1];
                f32x4 acc = {0.f, 0.f, 0.f, 0.f};
                for (int j = jb + slot; j < je; j += 4) {
                    const long long pc = __builtin_nontemporal_load(pairs + j);
                    const float v = __int_as_float((int)pc);
                    const int   c = (int)(pc >> 32);
                    const f32x4 xv = *reinterpret_cast<const f32x4*>(
                        Xsl + (size_t)c * SW_ + cg * 4);
                    acc += v * xv;
                }
                // reduce the 4 nnz-slots (xor 4, xor 8 within 16-lane group)
                acc.x += __shfl_xor(acc.x, 4); acc.y += __shfl_xor(acc.y, 4);
                acc.z += __shfl_xor(acc.z, 4); acc.w += __shfl_xor(acc.w, 4);
                acc.x += __shfl_xor(acc.x, 8); acc.y += __shfl_xor(acc.y, 8);
                acc.z += __shfl_xor(acc.z, 8); acc.w += __shfl_xor(acc.w, 8);
                if (slot == 0) {
                    const size_t off = ((size_t)s * M_ + r) * SW_ + cg * 4;
                    f32x4 res = scale * acc;
                    if (PV) {
                        const f32x4 pv = __builtin_nontemporal_load(
                            reinterpret_cast<const f32x4*>(PV + off));
                        res -= pv;
                    }
                    *reinterpret_cast<f32x4*>(Y + off) = res;   // cached: next phase gathers it
                }
            }
        }
        if (p < 2) gbar(&bar[p], nb);
    }
}

// ---------------------------------------------------------------------------
// fused final einsum: thread = (n, 2 consecutive m), all 32 o in registers.
// New layout: T_k[(n*M + m)*16 + f] -> fully contiguous 64 B per (term, m).
__global__ __launch_bounds__(256, 4) void k_final(
        const float* __restrict__ T0, const float* __restrict__ T1,
        const float* __restrict__ T2, const float* __restrict__ T3,
        const float* __restrict__ w, const float* __restrict__ b,
        float* __restrict__ out) {
    int t = blockIdx.x * blockDim.x + threadIdx.x;
    if (t >= MTILES_ * N_) return;
    const int n  = t & 7;
    const int m0 = (t >> 3) * MT_;

    float4 acc[MT_][8];
#pragma unroll
    for (int o4 = 0; o4 < 8; ++o4) {
        float4 bv = *reinterpret_cast<const float4*>(b + o4 * 4);
#pragma unroll
        for (int i = 0; i < MT_; ++i) acc[i][o4] = bv;
    }

    const float* Ts[4] = {T0, T1, T2, T3};
#pragma unroll
    for (int k = 0; k < KCH_; ++k) {
        const float* tk = Ts[k] + ((size_t)n * M_ + m0) * SW_;
#pragma unroll
        for (int f4 = 0; f4 < 4; ++f4) {
            const float4 a0 = *reinterpret_cast<const float4*>(tk + f4 * 4);
            const float4 a1 = *reinterpret_cast<const float4*>(tk + SW_ + f4 * 4);
            const float* e0 = reinterpret_cast<const float*>(&a0);
            const float* e1 = reinterpret_cast<const float*>(&a1);
#pragma unroll
            for (int e = 0; e < 4; ++e) {
                const int f = f4 * 4 + e;
                const float tv0 = e0[e], tv1 = e1[e];
                const float* wr = w + (f * KCH_ + k) * FOUT_;   // uniform
#pragma unroll
                for (int o4 = 0; o4 < 8; ++o4) {
                    float4 wv = *reinterpret_cast<const float4*>(wr + o4 * 4);
                    acc[0][o4].x += tv0 * wv.x; acc[0][o4].y += tv0 * wv.y;
                    acc[0][o4].z += tv0 * wv.z; acc[0][o4].w += tv0 * wv.w;
                    acc[1][o4].x += tv1 * wv.x; acc[1][o4].y += tv1 * wv.y;
                    acc[1][o4].z += tv1 * wv.z; acc[1][o4].w += tv1 * wv.w;
                }
            }
        }
    }

#pragma unroll
    for (int i = 0; i < MT_; ++i) {
        float* base = out + ((size_t)n * M_ + (m0 + i)) * FOUT_;
#pragma unroll
        for (int o4 = 0; o4 < 8; ++o4)
            *reinterpret_cast<float4*>(base + o4 * 4) = acc[i][o4];
    }
}

// ---------------------------------------------------------------------------
// Fallback path (small ws): per-term accumulation + separate slice spmm.
__global__ void k_accum(const float* __restrict__ T, const float* __restrict__ w,
                        const float* __restrict__ b, float* __restrict__ out,
                        int k, int init) {
    int t = blockIdx.x * blockDim.x + threadIdx.x;
    if (t >= M_ * FOUT_) return;
    int o = t & 31;
    int m = t >> 5;
    float acc[8];
#pragma unroll
    for (int n = 0; n < 8; ++n)
        acc[n] = init ? b[o] : out[((size_t)n * M_ + m) * FOUT_ + o];
#pragma unroll
    for (int n = 0; n < 8; ++n) {
        const float* tr = T + ((size_t)n * M_ + m) * SW_;
#pragma unroll
        for (int f4 = 0; f4 < 4; ++f4) {
            float4 tv = *reinterpret_cast<const float4*>(tr + f4 * 4);
            const float* ee = reinterpret_cast<const float*>(&tv);
#pragma unroll
            for (int e = 0; e < 4; ++e)
                acc[n] += ee[e] * w[((f4 * 4 + e) * KCH_ + k) * FOUT_ + o];
        }
    }
#pragma unroll
    for (int n = 0; n < 8; ++n)
        out[((size_t)n * M_ + m) * FOUT_ + o] = acc[n];
}

__global__ __launch_bounds__(256) void k_spmm_slice(
        const float* __restrict__ X, const float* __restrict__ prev,
        float* __restrict__ Y, const int* __restrict__ rp,
        const int2* __restrict__ pairs, float scale) {
    const int s  = blockIdx.x & 7;
    const int rb = blockIdx.x >> 3;
    const int r  = rb * RPB_ + (threadIdx.x >> 2);
    if (r >= M_) return;
    const int w4 = (threadIdx.x & 3) * 4;

    const float* Xs = X + (size_t)s * M_ * SW_;
    const size_t off = ((size_t)s * M_ + r) * SW_ + w4;

    f32x4 acc;
    if (prev) {
        f32x4 p = *reinterpret_cast<const f32x4*>(prev + off);
        acc = -p;
    } else {
        acc = (f32x4)0.f;
    }
    const long long* pr = reinterpret_cast<const long long*>(pairs);
    int jb = rp[r], je = rp[r + 1];
    for (int j = jb; j < je; ++j) {
        long long pc = pr[j];
        float v = scale * __int_as_float((int)pc);
        int   c = (int)(pc >> 32);
        f32x4 xv = *reinterpret_cast<const f32x4*>(Xs + (size_t)c * SW_ + w4);
        acc += v * xv;
    }
    *reinterpret_cast<f32x4*>(Y + off) = acc;
}

// ---------------------------------------------------------------------------
extern "C" void kernel_launch(void* const* d_in, const int* in_sizes, int n_in,
                              void* d_out, int out_size, void* d_ws, size_t ws_size,
                              hipStream_t stream) {
    const float* x    = (const float*)d_in[0];
    const float* vals = (const float*)d_in[1];
    const float* w    = (const float*)d_in[2];
    const float* b    = (const float*)d_in[3];
    const int*   row  = (const int*)d_in[4];
    const int*   col  = (const int*)d_in[5];
    float* out = (float*)d_out;

    const size_t tElems = (size_t)N_ * M_ * SW_;          // 6.4M floats per term
    const size_t csrBytes = (size_t)(M_ + 1) * 4 + (size_t)M_ * 4
                          + (size_t)NNZ_ * 8 + 2048 + 256;
    const size_t fusedBytes = 3 * tElems * 4 + csrBytes;  // ~84 MB
    const bool fused = ws_size >= fusedBytes;

    float* T1 = (float*)d_ws;
    float* T2 = T1 + tElems;
    float* T3 = fused ? (T2 + tElems) : nullptr;
    char*  p  = (char*)(fused ? (T3 + tElems) : (T2 + tElems));
    int*   row_ptr = (int*)p;              p += (size_t)(M_ + 1) * 4;
    int*   row_tmp = (int*)p;              p += (size_t)M_ * 4;
    int2*  pairs   = (int2*)p;             p += (size_t)NNZ_ * 8;
    int*   bsum    = (int*)p;              p += 1024;
    int*   boff    = (int*)p;              p += 1024;
    int*   syncw   = (int*)p;              // 26 ints (tickets + barriers)

    const int TB = 256;
    dim3 blk(TB);
    dim3 gN((NNZ_ + TB - 1) / TB);                 // per-nnz
    dim3 gS(RBLK_ * 8);                            // fallback spmm
    dim3 gF2((MTILES_ * N_ + TB - 1) / TB);        // k_final threads
    dim3 gF((M_ * FOUT_ + TB - 1) / TB);           // fallback k_accum

    // ---- build CSR (per call) ----
    hipMemsetAsync(row_tmp, 0, (size_t)M_ * 4, stream);     // row_tmp doubles as cnt
    hipMemsetAsync(syncw, 0, 128, stream);                  // tickets + barriers
    hipLaunchKernelGGL(k_hist,      gN, blk, 0, stream, row, row_tmp);
    hipLaunchKernelGGL(k_blocksum,  dim3(SCAN_NB), blk, 0, stream, row_tmp, bsum);
    hipLaunchKernelGGL(k_scan_bsum, dim3(1), blk, 0, stream, bsum, boff);
    hipLaunchKernelGGL(k_emit,      dim3(SCAN_NB), blk, 0, stream, row_tmp, boff,
                       row_ptr, row_tmp);
    hipLaunchKernelGGL(k_scatter,   gN, blk, 0, stream, vals, row, col, row_tmp, pairs);

    if (fused) {
        // T0 == x by construction of the slice layout.
        hipLaunchKernelGGL(k_mega, dim3(MEGA_BLOCKS_), blk, 0, stream,
                           x, row_ptr, (const long long*)pairs, T1, T2, T3, syncw);
        hipLaunchKernelGGL(k_final, gF2, blk, 0, stream, x, T1, T2, T3, w, b, out);
    } else {
        hipLaunchKernelGGL(k_accum, gF, blk, 0, stream, x, w, b, out, 0, 1);
        hipLaunchKernelGGL(k_spmm_slice, gS, blk, 0, stream, x, (const float*)nullptr,
                           T1, row_ptr, pairs, 1.0f);
        hipLaunchKernelGGL(k_accum, gF, blk, 0, stream, T1, w, b, out, 1, 0);
        hipLaunchKernelGGL(k_spmm_slice, gS, blk, 0, stream, T1, x, T2,
                           row_ptr, pairs, 2.0f);
        hipLaunchKernelGGL(k_accum, gF, blk, 0, stream, T2, w, b, out, 2, 0);
        hipLaunchKernelGGL(k_spmm_slice, gS, blk, 0, stream, T2, T1, T1,
                           row_ptr, pairs, 2.0f);   // prev aliases Y: same-thread RMW
        hipLaunchKernelGGL(k_accum, gF, blk, 0, stream, T1, w, b, out, 3, 0);
    }
}

// Round 9
// 594.147 us; speedup vs baseline: 1.4957x; 1.4957x over previous
//
#include <hip/hip_runtime.h>

// Problem constants (fixed-shape problem)
constexpr int N_    = 8;
constexpr int M_    = 50000;
constexpr int FIN_  = 16;
constexpr int FOUT_ = 32;
constexpr int KCH_  = 4;
constexpr int NNZ_  = 800000;
constexpr int SW_   = 16;                   // floats per slice row (= FIN_)
constexpr int SCAN_NB = (M_ + 255) / 256;   // 196 scan blocks
constexpr int MT_   = 2;                    // m-values per thread in k_final
constexpr int MTILES_ = M_ / MT_;           // 25000 m-tiles (exact)
constexpr int CH2_  = 64;                   // rows per spmm ticket chunk
constexpr int NCH2_ = (M_ + CH2_ - 1) / CH2_;   // 782 chunks per slice
constexpr int SPMM_BLOCKS_ = 2048;          // 8 blocks/CU
constexpr int RPB_  = 64;                   // fallback spmm rows/block
constexpr int RBLK_ = (M_ + RPB_ - 1) / RPB_;

// Slice mapping: col c = f*8+n of X0 -> slice s = n, w = f.
// Term layout T[(s*M + m)*16 + w] == x[n][m][f]  =>  T0 IS the input x.

typedef float f32x4 __attribute__((ext_vector_type(4)));

__device__ __forceinline__ int xcd_id() {
    int v;
    asm volatile("s_getreg_b32 %0, hwreg(HW_REG_XCC_ID)" : "=s"(v));
    return v & 7;
}

// ---------------------------------------------------------------------------
// CSR build
__global__ void k_hist(const int* __restrict__ row, int* __restrict__ cnt) {
    int i = blockIdx.x * blockDim.x + threadIdx.x;
    if (i < NNZ_) atomicAdd(&cnt[row[i]], 1);
}

__global__ void k_blocksum(const int* __restrict__ cnt, int* __restrict__ bsum) {
    __shared__ int s[256];
    int t = threadIdx.x;
    int idx = blockIdx.x * 256 + t;
    s[t] = (idx < M_) ? cnt[idx] : 0;
    __syncthreads();
    for (int off = 128; off > 0; off >>= 1) {
        if (t < off) s[t] += s[t + off];
        __syncthreads();
    }
    if (t == 0) bsum[blockIdx.x] = s[0];
}

__global__ void k_scan_bsum(const int* __restrict__ bsum, int* __restrict__ boff) {
    __shared__ int s[256];
    int t = threadIdx.x;
    int v = (t < SCAN_NB) ? bsum[t] : 0;
    s[t] = v;
    __syncthreads();
    for (int off = 1; off < 256; off <<= 1) {
        int a = (t >= off) ? s[t - off] : 0;
        __syncthreads();
        s[t] += a;
        __syncthreads();
    }
    if (t < SCAN_NB) boff[t] = s[t] - v;   // exclusive
}

__global__ void k_emit(const int* __restrict__ cnt, const int* __restrict__ boff,
                       int* __restrict__ row_ptr, int* __restrict__ row_tmp) {
    __shared__ int s[256];
    int t = threadIdx.x;
    int idx = blockIdx.x * 256 + t;
    int v = (idx < M_) ? cnt[idx] : 0;
    s[t] = v;
    __syncthreads();
    for (int off = 1; off < 256; off <<= 1) {
        int a = (t >= off) ? s[t - off] : 0;
        __syncthreads();
        s[t] += a;
        __syncthreads();
    }
    if (idx < M_) {
        int r = boff[blockIdx.x] + s[t] - v;
        row_ptr[idx] = r;
        row_tmp[idx] = r;
    }
    if (idx == 0) row_ptr[M_] = NNZ_;
}

__global__ void k_scatter(const float* __restrict__ vals, const int* __restrict__ row,
                          const int* __restrict__ col, int* __restrict__ row_tmp,
                          int2* __restrict__ pairs) {
    int i = blockIdx.x * blockDim.x + threadIdx.x;
    if (i >= NNZ_) return;
    int p = atomicAdd(&row_tmp[row[i]], 1);
    pairs[p] = make_int2(__float_as_int(vals[i]), col[i]);
}

// ---------------------------------------------------------------------------
// XCD-pinned slice SpMM: each block processes only its own XCD's slice, so
// the 3.2 MB X slice stays resident in that XCD's private 4 MB L2.
// Cache policy: X / pairs / rp plain (cached); prev nt-load, Y nt-store
// (streams must not evict the resident X slice).
// One quad (4 lanes) per row; per-slice atomic tickets of 64 rows.
__global__ __launch_bounds__(256) void k_spmm_x(
        const float* __restrict__ X, const float* __restrict__ prev,
        float* __restrict__ Y, const int* __restrict__ rp,
        const long long* __restrict__ pairs, float scale,
        int* __restrict__ ticket) {
    const int s = xcd_id();
    __shared__ int sh_ck;
    const int quad = threadIdx.x >> 2;     // 0..63: row within chunk
    const int cg   = threadIdx.x & 3;      // 4-float group within 16-float row
    const float* Xs = X + (size_t)s * M_ * SW_;

    for (;;) {
        __syncthreads();
        if (threadIdx.x == 0)
            sh_ck = __hip_atomic_fetch_add(&ticket[s], 1, __ATOMIC_RELAXED,
                                           __HIP_MEMORY_SCOPE_AGENT);
        __syncthreads();
        const int ck = sh_ck;               // uniform across block
        if (ck >= NCH2_) return;
        const int r = ck * CH2_ + quad;
        if (r >= M_) continue;              // tail chunk: idle quads re-sync at top

        const int jb = rp[r], je = rp[r + 1];
        f32x4 acc = {0.f, 0.f, 0.f, 0.f};
        for (int j = jb; j < je; ++j) {
            const long long pc = pairs[j];          // cached: sequential stream
            const float v = __int_as_float((int)pc);
            const int   c = (int)(pc >> 32);
            const f32x4 xv = *reinterpret_cast<const f32x4*>(
                Xs + (size_t)c * SW_ + cg * 4);     // cached: L2-resident slice
            acc += v * xv;
        }
        const size_t off = ((size_t)s * M_ + r) * SW_ + cg * 4;
        f32x4 res = scale * acc;
        if (prev) {
            const f32x4 pv = __builtin_nontemporal_load(
                reinterpret_cast<const f32x4*>(prev + off));
            res -= pv;
        }
        __builtin_nontemporal_store(res, reinterpret_cast<f32x4*>(Y + off));
    }
}

// ---------------------------------------------------------------------------
// fused final einsum: thread = (n, 2 consecutive m), all 32 o in registers.
// Layout: T_k[(n*M + m)*16 + f] -> fully contiguous 64 B per (term, m).
__global__ __launch_bounds__(256, 4) void k_final(
        const float* __restrict__ T0, const float* __restrict__ T1,
        const float* __restrict__ T2, const float* __restrict__ T3,
        const float* __restrict__ w, const float* __restrict__ b,
        float* __restrict__ out) {
    int t = blockIdx.x * blockDim.x + threadIdx.x;
    if (t >= MTILES_ * N_) return;
    const int n  = t & 7;
    const int m0 = (t >> 3) * MT_;

    float4 acc[MT_][8];
#pragma unroll
    for (int o4 = 0; o4 < 8; ++o4) {
        float4 bv = *reinterpret_cast<const float4*>(b + o4 * 4);
#pragma unroll
        for (int i = 0; i < MT_; ++i) acc[i][o4] = bv;
    }

    const float* Ts[4] = {T0, T1, T2, T3};
#pragma unroll
    for (int k = 0; k < KCH_; ++k) {
        const float* tk = Ts[k] + ((size_t)n * M_ + m0) * SW_;
#pragma unroll
        for (int f4 = 0; f4 < 4; ++f4) {
            const float4 a0 = *reinterpret_cast<const float4*>(tk + f4 * 4);
            const float4 a1 = *reinterpret_cast<const float4*>(tk + SW_ + f4 * 4);
            const float* e0 = reinterpret_cast<const float*>(&a0);
            const float* e1 = reinterpret_cast<const float*>(&a1);
#pragma unroll
            for (int e = 0; e < 4; ++e) {
                const int f = f4 * 4 + e;
                const float tv0 = e0[e], tv1 = e1[e];
                const float* wr = w + (f * KCH_ + k) * FOUT_;   // uniform
#pragma unroll
                for (int o4 = 0; o4 < 8; ++o4) {
                    float4 wv = *reinterpret_cast<const float4*>(wr + o4 * 4);
                    acc[0][o4].x += tv0 * wv.x; acc[0][o4].y += tv0 * wv.y;
                    acc[0][o4].z += tv0 * wv.z; acc[0][o4].w += tv0 * wv.w;
                    acc[1][o4].x += tv1 * wv.x; acc[1][o4].y += tv1 * wv.y;
                    acc[1][o4].z += tv1 * wv.z; acc[1][o4].w += tv1 * wv.w;
                }
            }
        }
    }

#pragma unroll
    for (int i = 0; i < MT_; ++i) {
        float* base = out + ((size_t)n * M_ + (m0 + i)) * FOUT_;
#pragma unroll
        for (int o4 = 0; o4 < 8; ++o4)
            *reinterpret_cast<float4*>(base + o4 * 4) = acc[i][o4];
    }
}

// ---------------------------------------------------------------------------
// Fallback path (small ws): per-term accumulation + plain slice spmm.
__global__ void k_accum(const float* __restrict__ T, const float* __restrict__ w,
                        const float* __restrict__ b, float* __restrict__ out,
                        int k, int init) {
    int t = blockIdx.x * blockDim.x + threadIdx.x;
    if (t >= M_ * FOUT_) return;
    int o = t & 31;
    int m = t >> 5;
    float acc[8];
#pragma unroll
    for (int n = 0; n < 8; ++n)
        acc[n] = init ? b[o] : out[((size_t)n * M_ + m) * FOUT_ + o];
#pragma unroll
    for (int n = 0; n < 8; ++n) {
        const float* tr = T + ((size_t)n * M_ + m) * SW_;
#pragma unroll
        for (int f4 = 0; f4 < 4; ++f4) {
            float4 tv = *reinterpret_cast<const float4*>(tr + f4 * 4);
            const float* ee = reinterpret_cast<const float*>(&tv);
#pragma unroll
            for (int e = 0; e < 4; ++e)
                acc[n] += ee[e] * w[((f4 * 4 + e) * KCH_ + k) * FOUT_ + o];
        }
    }
#pragma unroll
    for (int n = 0; n < 8; ++n)
        out[((size_t)n * M_ + m) * FOUT_ + o] = acc[n];
}

__global__ __launch_bounds__(256) void k_spmm_slice(
        const float* __restrict__ X, const float* __restrict__ prev,
        float* __restrict__ Y, const int* __restrict__ rp,
        const int2* __restrict__ pairs, float scale) {
    const int s  = blockIdx.x & 7;
    const int rb = blockIdx.x >> 3;
    const int r  = rb * RPB_ + (threadIdx.x >> 2);
    if (r >= M_) return;
    const int w4 = (threadIdx.x & 3) * 4;

    const float* Xs = X + (size_t)s * M_ * SW_;
    const size_t off = ((size_t)s * M_ + r) * SW_ + w4;

    f32x4 acc;
    if (prev) {
        f32x4 p = *reinterpret_cast<const f32x4*>(prev + off);
        acc = -p;
    } else {
        acc = (f32x4)0.f;
    }
    const long long* pr = reinterpret_cast<const long long*>(pairs);
    int jb = rp[r], je = rp[r + 1];
    for (int j = jb; j < je; ++j) {
        long long pc = pr[j];
        float v = scale * __int_as_float((int)pc);
        int   c = (int)(pc >> 32);
        f32x4 xv = *reinterpret_cast<const f32x4*>(Xs + (size_t)c * SW_ + w4);
        acc += v * xv;
    }
    *reinterpret_cast<f32x4*>(Y + off) = acc;
}

// ---------------------------------------------------------------------------
extern "C" void kernel_launch(void* const* d_in, const int* in_sizes, int n_in,
                              void* d_out, int out_size, void* d_ws, size_t ws_size,
                              hipStream_t stream) {
    const float* x    = (const float*)d_in[0];
    const float* vals = (const float*)d_in[1];
    const float* w    = (const float*)d_in[2];
    const float* b    = (const float*)d_in[3];
    const int*   row  = (const int*)d_in[4];
    const int*   col  = (const int*)d_in[5];
    float* out = (float*)d_out;

    const size_t tElems = (size_t)N_ * M_ * SW_;          // 6.4M floats per term
    const size_t csrBytes = (size_t)(M_ + 1) * 4 + (size_t)M_ * 4
                          + (size_t)NNZ_ * 8 + 2048 + 256;
    const size_t fusedBytes = 3 * tElems * 4 + csrBytes;  // ~84 MB
    const bool fused = ws_size >= fusedBytes;

    float* T1 = (float*)d_ws;
    float* T2 = T1 + tElems;
    float* T3 = fused ? (T2 + tElems) : nullptr;
    char*  p  = (char*)(fused ? (T3 + tElems) : (T2 + tElems));
    int*   row_ptr = (int*)p;              p += (size_t)(M_ + 1) * 4;
    int*   row_tmp = (int*)p;              p += (size_t)M_ * 4;
    int2*  pairs   = (int2*)p;             p += (size_t)NNZ_ * 8;
    int*   bsum    = (int*)p;              p += 1024;
    int*   boff    = (int*)p;              p += 1024;
    int*   tickets = (int*)p;              // 3 phases x 8 slices

    const int TB = 256;
    dim3 blk(TB);
    dim3 gN((NNZ_ + TB - 1) / TB);                 // per-nnz
    dim3 gX(SPMM_BLOCKS_);                         // XCD-pinned spmm
    dim3 gS(RBLK_ * 8);                            // fallback spmm
    dim3 gF2((MTILES_ * N_ + TB - 1) / TB);        // k_final threads
    dim3 gF((M_ * FOUT_ + TB - 1) / TB);           // fallback k_accum

    // ---- build CSR (per call) ----
    hipMemsetAsync(row_tmp, 0, (size_t)M_ * 4, stream);     // row_tmp doubles as cnt
    hipMemsetAsync(tickets, 0, 128, stream);
    hipLaunchKernelGGL(k_hist,      gN, blk, 0, stream, row, row_tmp);
    hipLaunchKernelGGL(k_blocksum,  dim3(SCAN_NB), blk, 0, stream, row_tmp, bsum);
    hipLaunchKernelGGL(k_scan_bsum, dim3(1), blk, 0, stream, bsum, boff);
    hipLaunchKernelGGL(k_emit,      dim3(SCAN_NB), blk, 0, stream, row_tmp, boff,
                       row_ptr, row_tmp);
    hipLaunchKernelGGL(k_scatter,   gN, blk, 0, stream, vals, row, col, row_tmp, pairs);

    if (fused) {
        // T0 == x by construction of the slice layout.
        hipLaunchKernelGGL(k_spmm_x, gX, blk, 0, stream, x, (const float*)nullptr,
                           T1, row_ptr, (const long long*)pairs, 1.0f, tickets);
        hipLaunchKernelGGL(k_spmm_x, gX, blk, 0, stream, T1, x,
                           T2, row_ptr, (const long long*)pairs, 2.0f, tickets + 8);
        hipLaunchKernelGGL(k_spmm_x, gX, blk, 0, stream, T2, T1,
                           T3, row_ptr, (const long long*)pairs, 2.0f, tickets + 16);
        hipLaunchKernelGGL(k_final, gF2, blk, 0, stream, x, T1, T2, T3, w, b, out);
    } else {
        hipLaunchKernelGGL(k_accum, gF, blk, 0, stream, x, w, b, out, 0, 1);
        hipLaunchKernelGGL(k_spmm_slice, gS, blk, 0, stream, x, (const float*)nullptr,
                           T1, row_ptr, pairs, 1.0f);
        hipLaunchKernelGGL(k_accum, gF, blk, 0, stream, T1, w, b, out, 1, 0);
        hipLaunchKernelGGL(k_spmm_slice, gS, blk, 0, stream, T1, x, T2,
                           row_ptr, pairs, 2.0f);
        hipLaunchKernelGGL(k_accum, gF, blk, 0, stream, T2, w, b, out, 2, 0);
        hipLaunchKernelGGL(k_spmm_slice, gS, blk, 0, stream, T2, T1, T1,
                           row_ptr, pairs, 2.0f);   // prev aliases Y: same-thread RMW
        hipLaunchKernelGGL(k_accum, gF, blk, 0, stream, T1, w, b, out, 3, 0);
    }
}

// Round 10
// 281.355 us; speedup vs baseline: 3.1586x; 2.1117x over previous
//
#include <hip/hip_runtime.h>

// Problem constants (fixed-shape problem)
constexpr int N_    = 8;
constexpr int M_    = 50000;
constexpr int FIN_  = 16;
constexpr int FOUT_ = 32;
constexpr int KCH_  = 4;
constexpr int NNZ_  = 800000;
constexpr int ROWB_ = 128;                  // bf16 elems per term row (256 B)
constexpr int SCAN_NB = (M_ + 255) / 256;   // 196 scan blocks
constexpr int MT_   = 2;                    // m-values per thread in k_final
constexpr int MTILES_ = M_ / MT_;           // 25000 m-tiles (exact)
constexpr int RPBLK_ = 8;                   // rows per spmm block (256 thr / 32)

typedef float f32x4 __attribute__((ext_vector_type(4)));

__device__ __forceinline__ float bf2f(unsigned short u) {
    return __uint_as_float(((unsigned int)u) << 16);
}
__device__ __forceinline__ unsigned short f2bf(float f) {   // RNE
    unsigned int u = __float_as_uint(f);
    return (unsigned short)((u + 0x7fffu + ((u >> 16) & 1u)) >> 16);
}

// ---------------------------------------------------------------------------
// X0 bf16: X0[m][f*8+n] = x[n][m][f]
__global__ void k_build_x0(const float* __restrict__ x, unsigned short* __restrict__ t0) {
    int t = blockIdx.x * blockDim.x + threadIdx.x;
    if (t >= M_ * ROWB_) return;
    int c = t & 127, m = t >> 7;
    int f = c >> 3, n = c & 7;
    t0[t] = f2bf(x[((size_t)n * M_ + m) * FIN_ + f]);
}

// ---------------------------------------------------------------------------
// CSR build
__global__ void k_hist(const int* __restrict__ row, int* __restrict__ cnt) {
    int i = blockIdx.x * blockDim.x + threadIdx.x;
    if (i < NNZ_) atomicAdd(&cnt[row[i]], 1);
}

__global__ void k_blocksum(const int* __restrict__ cnt, int* __restrict__ bsum) {
    __shared__ int s[256];
    int t = threadIdx.x;
    int idx = blockIdx.x * 256 + t;
    s[t] = (idx < M_) ? cnt[idx] : 0;
    __syncthreads();
    for (int off = 128; off > 0; off >>= 1) {
        if (t < off) s[t] += s[t + off];
        __syncthreads();
    }
    if (t == 0) bsum[blockIdx.x] = s[0];
}

__global__ void k_scan_bsum(const int* __restrict__ bsum, int* __restrict__ boff) {
    __shared__ int s[256];
    int t = threadIdx.x;
    int v = (t < SCAN_NB) ? bsum[t] : 0;
    s[t] = v;
    __syncthreads();
    for (int off = 1; off < 256; off <<= 1) {
        int a = (t >= off) ? s[t - off] : 0;
        __syncthreads();
        s[t] += a;
        __syncthreads();
    }
    if (t < SCAN_NB) boff[t] = s[t] - v;   // exclusive
}

__global__ void k_emit(const int* __restrict__ cnt, const int* __restrict__ boff,
                       int* __restrict__ row_ptr, int* __restrict__ row_tmp) {
    __shared__ int s[256];
    int t = threadIdx.x;
    int idx = blockIdx.x * 256 + t;
    int v = (idx < M_) ? cnt[idx] : 0;
    s[t] = v;
    __syncthreads();
    for (int off = 1; off < 256; off <<= 1) {
        int a = (t >= off) ? s[t - off] : 0;
        __syncthreads();
        s[t] += a;
        __syncthreads();
    }
    if (idx < M_) {
        int r = boff[blockIdx.x] + s[t] - v;
        row_ptr[idx] = r;
        row_tmp[idx] = r;
    }
    if (idx == 0) row_ptr[M_] = NNZ_;
}

__global__ void k_scatter(const float* __restrict__ vals, const int* __restrict__ row,
                          const int* __restrict__ col, int* __restrict__ row_tmp,
                          int2* __restrict__ pairs) {
    int i = blockIdx.x * blockDim.x + threadIdx.x;
    if (i >= NNZ_) return;
    int p = atomicAdd(&row_tmp[row[i]], 1);
    pairs[p] = make_int2(__float_as_int(vals[i]), col[i]);
}

// ---------------------------------------------------------------------------
// bf16 SpMM: Y[r,:] = scale * sum_j v_j * X[c_j,:]  (- prev[r,:] if prev)
// 32 lanes per row (256 B bf16 row), fp32 accumulate, j unrolled x2 for MLP.
__global__ __launch_bounds__(256) void k_spmm_bf16(
        const unsigned short* __restrict__ X, const unsigned short* __restrict__ prev,
        unsigned short* __restrict__ Y, const int* __restrict__ rp,
        const long long* __restrict__ pairs, float scale) {
    const int r = blockIdx.x * RPBLK_ + (threadIdx.x >> 5);
    if (r >= M_) return;
    const int lane = threadIdx.x & 31;
    const size_t off = (size_t)r * ROWB_ + lane * 4;

    const int jb = rp[r], je = rp[r + 1];
    f32x4 a0 = {0.f, 0.f, 0.f, 0.f}, a1 = {0.f, 0.f, 0.f, 0.f};
    int j = jb;
    for (; j + 1 < je; j += 2) {
        const long long p0 = pairs[j], p1 = pairs[j + 1];
        const float v0 = __int_as_float((int)p0);
        const float v1 = __int_as_float((int)p1);
        const int   c0 = (int)(p0 >> 32), c1 = (int)(p1 >> 32);
        const ushort4 u0 = *reinterpret_cast<const ushort4*>(X + (size_t)c0 * ROWB_ + lane * 4);
        const ushort4 u1 = *reinterpret_cast<const ushort4*>(X + (size_t)c1 * ROWB_ + lane * 4);
        const f32x4 x0 = {bf2f(u0.x), bf2f(u0.y), bf2f(u0.z), bf2f(u0.w)};
        const f32x4 x1 = {bf2f(u1.x), bf2f(u1.y), bf2f(u1.z), bf2f(u1.w)};
        a0 += v0 * x0;
        a1 += v1 * x1;
    }
    if (j < je) {
        const long long p0 = pairs[j];
        const float v0 = __int_as_float((int)p0);
        const int   c0 = (int)(p0 >> 32);
        const ushort4 u0 = *reinterpret_cast<const ushort4*>(X + (size_t)c0 * ROWB_ + lane * 4);
        const f32x4 x0 = {bf2f(u0.x), bf2f(u0.y), bf2f(u0.z), bf2f(u0.w)};
        a0 += v0 * x0;
    }
    f32x4 res = scale * (a0 + a1);
    if (prev) {
        const ushort4 pv = *reinterpret_cast<const ushort4*>(prev + off);
        const f32x4 pf = {bf2f(pv.x), bf2f(pv.y), bf2f(pv.z), bf2f(pv.w)};
        res -= pf;
    }
    ushort4 o;
    o.x = f2bf(res.x); o.y = f2bf(res.y); o.z = f2bf(res.z); o.w = f2bf(res.w);
    *reinterpret_cast<ushort4*>(Y + off) = o;
}

// ---------------------------------------------------------------------------
// fused final einsum (bf16 terms): thread = (n, 2 consecutive m), 32 o in regs.
__global__ __launch_bounds__(256, 4) void k_final(
        const unsigned short* __restrict__ T0, const unsigned short* __restrict__ T1,
        const unsigned short* __restrict__ T2, const unsigned short* __restrict__ T3,
        const float* __restrict__ w, const float* __restrict__ b,
        float* __restrict__ out) {
    int t = blockIdx.x * blockDim.x + threadIdx.x;
    if (t >= MTILES_ * N_) return;
    const int n  = t & 7;
    const int m0 = (t >> 3) * MT_;

    float4 acc[MT_][8];
#pragma unroll
    for (int o4 = 0; o4 < 8; ++o4) {
        float4 bv = *reinterpret_cast<const float4*>(b + o4 * 4);
#pragma unroll
        for (int i = 0; i < MT_; ++i) acc[i][o4] = bv;
    }

    const unsigned short* Ts[4] = {T0, T1, T2, T3};
#pragma unroll
    for (int k = 0; k < KCH_; ++k) {
        const unsigned short* tk = Ts[k] + (size_t)m0 * ROWB_ + n;
#pragma unroll
        for (int f = 0; f < FIN_; ++f) {
            const float tv0 = bf2f(tk[f * 8]);
            const float tv1 = bf2f(tk[ROWB_ + f * 8]);
            const float* wr = w + (f * KCH_ + k) * FOUT_;   // uniform
#pragma unroll
            for (int o4 = 0; o4 < 8; ++o4) {
                float4 wv = *reinterpret_cast<const float4*>(wr + o4 * 4);
                acc[0][o4].x += tv0 * wv.x; acc[0][o4].y += tv0 * wv.y;
                acc[0][o4].z += tv0 * wv.z; acc[0][o4].w += tv0 * wv.w;
                acc[1][o4].x += tv1 * wv.x; acc[1][o4].y += tv1 * wv.y;
                acc[1][o4].z += tv1 * wv.z; acc[1][o4].w += tv1 * wv.w;
            }
        }
    }

#pragma unroll
    for (int i = 0; i < MT_; ++i) {
        float* base = out + ((size_t)n * M_ + (m0 + i)) * FOUT_;
#pragma unroll
        for (int o4 = 0; o4 < 8; ++o4)
            *reinterpret_cast<float4*>(base + o4 * 4) = acc[i][o4];
    }
}

// ---------------------------------------------------------------------------
// fallback per-term accumulation (bf16 term)
__global__ __launch_bounds__(256, 4) void k_accum(
        const unsigned short* __restrict__ T, const float* __restrict__ w,
        const float* __restrict__ b, float* __restrict__ out, int k, int init) {
    int t = blockIdx.x * blockDim.x + threadIdx.x;
    if (t >= MTILES_ * N_) return;
    const int n  = t & 7;
    const int m0 = (t >> 3) * MT_;

    float4 acc[MT_][8];
#pragma unroll
    for (int i = 0; i < MT_; ++i) {
        float* base = out + ((size_t)n * M_ + (m0 + i)) * FOUT_;
#pragma unroll
        for (int o4 = 0; o4 < 8; ++o4) {
            if (init) {
                float4 bv = *reinterpret_cast<const float4*>(b + o4 * 4);
                acc[i][o4] = bv;
            } else {
                acc[i][o4] = *reinterpret_cast<const float4*>(base + o4 * 4);
            }
        }
    }
    const unsigned short* tk = T + (size_t)m0 * ROWB_ + n;
#pragma unroll
    for (int f = 0; f < FIN_; ++f) {
        const float tv0 = bf2f(tk[f * 8]);
        const float tv1 = bf2f(tk[ROWB_ + f * 8]);
        const float* wr = w + (f * KCH_ + k) * FOUT_;
#pragma unroll
        for (int o4 = 0; o4 < 8; ++o4) {
            float4 wv = *reinterpret_cast<const float4*>(wr + o4 * 4);
            acc[0][o4].x += tv0 * wv.x; acc[0][o4].y += tv0 * wv.y;
            acc[0][o4].z += tv0 * wv.z; acc[0][o4].w += tv0 * wv.w;
            acc[1][o4].x += tv1 * wv.x; acc[1][o4].y += tv1 * wv.y;
            acc[1][o4].z += tv1 * wv.z; acc[1][o4].w += tv1 * wv.w;
        }
    }
#pragma unroll
    for (int i = 0; i < MT_; ++i) {
        float* base = out + ((size_t)n * M_ + (m0 + i)) * FOUT_;
#pragma unroll
        for (int o4 = 0; o4 < 8; ++o4)
            *reinterpret_cast<float4*>(base + o4 * 4) = acc[i][o4];
    }
}

// ---------------------------------------------------------------------------
extern "C" void kernel_launch(void* const* d_in, const int* in_sizes, int n_in,
                              void* d_out, int out_size, void* d_ws, size_t ws_size,
                              hipStream_t stream) {
    const float* x    = (const float*)d_in[0];
    const float* vals = (const float*)d_in[1];
    const float* w    = (const float*)d_in[2];
    const float* b    = (const float*)d_in[3];
    const int*   row  = (const int*)d_in[4];
    const int*   col  = (const int*)d_in[5];
    float* out = (float*)d_out;

    const size_t tElems = (size_t)M_ * ROWB_;             // 6.4M bf16 per term
    const size_t tBytes = tElems * 2;                     // 12.8 MB
    const size_t csrBytes = (size_t)(M_ + 1) * 4 + (size_t)M_ * 4
                          + (size_t)NNZ_ * 8 + 2048;
    const size_t fusedBytes = 4 * tBytes + csrBytes;      // ~58 MB
    const size_t fbBytes    = 3 * tBytes + csrBytes;      // ~45 MB
    const bool fused = ws_size >= fusedBytes;

    unsigned short* X0 = (unsigned short*)d_ws;
    unsigned short* T1 = X0 + tElems;
    unsigned short* T2 = T1 + tElems;
    unsigned short* T3 = fused ? (T2 + tElems) : T1;      // fallback: in-place
    char* p = (char*)(fused ? (T3 + tElems) : (T2 + tElems));
    int*  row_ptr = (int*)p;               p += (size_t)(M_ + 1) * 4;
    int*  row_tmp = (int*)p;               p += (size_t)M_ * 4;
    int2* pairs   = (int2*)p;              p += (size_t)NNZ_ * 8;
    int*  bsum    = (int*)p;               p += 1024;
    int*  boff    = (int*)p;
    (void)fbBytes;

    const int TB = 256;
    dim3 blk(TB);
    dim3 gN((NNZ_ + TB - 1) / TB);                 // per-nnz
    dim3 gX((M_ * ROWB_ + TB - 1) / TB);           // build_x0
    dim3 gS((M_ + RPBLK_ - 1) / RPBLK_);           // spmm: 8 rows per block
    dim3 gF((MTILES_ * N_ + TB - 1) / TB);         // final / accum

    // ---- build CSR (per call) ----
    hipMemsetAsync(row_tmp, 0, (size_t)M_ * 4, stream);     // row_tmp doubles as cnt
    hipLaunchKernelGGL(k_hist,      gN, blk, 0, stream, row, row_tmp);
    hipLaunchKernelGGL(k_blocksum,  dim3(SCAN_NB), blk, 0, stream, row_tmp, bsum);
    hipLaunchKernelGGL(k_scan_bsum, dim3(1), blk, 0, stream, bsum, boff);
    hipLaunchKernelGGL(k_emit,      dim3(SCAN_NB), blk, 0, stream, row_tmp, boff,
                       row_ptr, row_tmp);
    hipLaunchKernelGGL(k_scatter,   gN, blk, 0, stream, vals, row, col, row_tmp, pairs);

    // ---- X0 (bf16) ----
    hipLaunchKernelGGL(k_build_x0, gX, blk, 0, stream, x, X0);

    const long long* pr = (const long long*)pairs;
    if (fused) {
        hipLaunchKernelGGL(k_spmm_bf16, gS, blk, 0, stream, X0, (const unsigned short*)nullptr,
                           T1, row_ptr, pr, 1.0f);
        hipLaunchKernelGGL(k_spmm_bf16, gS, blk, 0, stream, T1, X0, T2, row_ptr, pr, 2.0f);
        hipLaunchKernelGGL(k_spmm_bf16, gS, blk, 0, stream, T2, T1, T3, row_ptr, pr, 2.0f);
        hipLaunchKernelGGL(k_final, gF, blk, 0, stream, X0, T1, T2, T3, w, b, out);
    } else {
        hipLaunchKernelGGL(k_accum, gF, blk, 0, stream, X0, w, b, out, 0, 1);
        hipLaunchKernelGGL(k_spmm_bf16, gS, blk, 0, stream, X0, (const unsigned short*)nullptr,
                           T1, row_ptr, pr, 1.0f);
        hipLaunchKernelGGL(k_accum, gF, blk, 0, stream, T1, w, b, out, 1, 0);
        hipLaunchKernelGGL(k_spmm_bf16, gS, blk, 0, stream, T1, X0, T2, row_ptr, pr, 2.0f);
        hipLaunchKernelGGL(k_accum, gF, blk, 0, stream, T2, w, b, out, 2, 0);
        // T3 overwrites T1 in place: each element read (prev) then written by the
        // same thread -> no cross-thread hazard.
        hipLaunchKernelGGL(k_spmm_bf16, gS, blk, 0, stream, T2, T1, T1, row_ptr, pr, 2.0f);
        hipLaunchKernelGGL(k_accum, gF, blk, 0, stream, T1, w, b, out, 3, 0);
    }
}

// Round 12
// 255.312 us; speedup vs baseline: 3.4808x; 1.1020x over previous
//
#include <hip/hip_runtime.h>

// Problem constants (fixed-shape problem)
constexpr int N_    = 8;
constexpr int M_    = 50000;
constexpr int FIN_  = 16;
constexpr int FOUT_ = 32;
constexpr int KCH_  = 4;
constexpr int NNZ_  = 800000;
constexpr int ROWB_ = 128;                  // bf16 elems per term row (256 B)
constexpr int SCAN_NB = (M_ + 255) / 256;   // 196 scan blocks
constexpr int MT_   = 2;                    // m-values per thread in k_final
constexpr int MTILES_ = M_ / MT_;           // 25000 m-tiles (exact)
constexpr int RPBLK_ = 8;                   // rows per spmm block (256 thr / 32)
constexpr int NBKT_  = (M_ + 255) / 256;    // 196 row-buckets (256 rows each)
constexpr int BSC_BLOCKS_ = 256;            // bucket-scatter blocks
constexpr int CHUNK_ = NNZ_ / BSC_BLOCKS_;  // 3125 nnz per block (exact)

typedef float f32x4 __attribute__((ext_vector_type(4)));

__device__ __forceinline__ float bf2f(unsigned short u) {
    return __uint_as_float(((unsigned int)u) << 16);
}
__device__ __forceinline__ unsigned short f2bf(float f) {   // RNE
    unsigned int u = __float_as_uint(f);
    return (unsigned short)((u + 0x7fffu + ((u >> 16) & 1u)) >> 16);
}

// ---------------------------------------------------------------------------
// X0 bf16: X0[m][f*8+n] = x[n][m][f]
__global__ void k_build_x0(const float* __restrict__ x, unsigned short* __restrict__ t0) {
    int t = blockIdx.x * blockDim.x + threadIdx.x;
    if (t >= M_ * ROWB_) return;
    int c = t & 127, m = t >> 7;
    int f = c >> 3, n = c & 7;
    t0[t] = f2bf(x[((size_t)n * M_ + m) * FIN_ + f]);
}

// ---------------------------------------------------------------------------
// CSR row_ptr build (hist + hierarchical scan)
__global__ void k_hist(const int* __restrict__ row, int* __restrict__ cnt) {
    int i = blockIdx.x * blockDim.x + threadIdx.x;
    if (i < NNZ_) atomicAdd(&cnt[row[i]], 1);
}

__global__ void k_blocksum(const int* __restrict__ cnt, int* __restrict__ bsum) {
    __shared__ int s[256];
    int t = threadIdx.x;
    int idx = blockIdx.x * 256 + t;
    s[t] = (idx < M_) ? cnt[idx] : 0;
    __syncthreads();
    for (int off = 128; off > 0; off >>= 1) {
        if (t < off) s[t] += s[t + off];
        __syncthreads();
    }
    if (t == 0) bsum[blockIdx.x] = s[0];
}

__global__ void k_scan_bsum(const int* __restrict__ bsum, int* __restrict__ boff) {
    __shared__ int s[256];
    int t = threadIdx.x;
    int v = (t < SCAN_NB) ? bsum[t] : 0;
    s[t] = v;
    __syncthreads();
    for (int off = 1; off < 256; off <<= 1) {
        int a = (t >= off) ? s[t - off] : 0;
        __syncthreads();
        s[t] += a;
        __syncthreads();
    }
    if (t < SCAN_NB) boff[t] = s[t] - v;   // exclusive
}

__global__ void k_emit(const int* __restrict__ cnt, const int* __restrict__ boff,
                       int* __restrict__ row_ptr) {
    __shared__ int s[256];
    int t = threadIdx.x;
    int idx = blockIdx.x * 256 + t;
    int v = (idx < M_) ? cnt[idx] : 0;
    s[t] = v;
    __syncthreads();
    for (int off = 1; off < 256; off <<= 1) {
        int a = (t >= off) ? s[t - off] : 0;
        __syncthreads();
        s[t] += a;
        __syncthreads();
    }
    if (idx < M_) row_ptr[idx] = boff[blockIdx.x] + s[t] - v;
    if (idx == 0) row_ptr[M_] = NNZ_;
}

// bticket[b] = row_ptr[b*256] (bucket staging base = its CSR region base)
__global__ void k_binit(const int* __restrict__ row_ptr, int* __restrict__ bticket) {
    int b = blockIdx.x * blockDim.x + threadIdx.x;
    if (b < NBKT_) bticket[b] = row_ptr[b * 256];
}

// ---------------------------------------------------------------------------
// Phase 1: bucket scatter. Each block LDS-histograms its nnz chunk over the
// 196 buckets, reserves space with ONE global atomic per (block,bucket), then
// writes entries sequentially per bucket region -> full-line writes.
// Entry: word0 = val bits, word1 = col | rowlocal<<16 (col < 2^16).
__global__ __launch_bounds__(256) void k_bscatter(
        const float* __restrict__ vals, const int* __restrict__ row,
        const int* __restrict__ col, int* __restrict__ bticket,
        int2* __restrict__ stage) {
    __shared__ int cnt[NBKT_];
    __shared__ int base[NBKT_];
    const int t = threadIdx.x;
    const int i0 = blockIdx.x * CHUNK_;
    for (int b = t; b < NBKT_; b += 256) cnt[b] = 0;
    __syncthreads();
    for (int i = i0 + t; i < i0 + CHUNK_; i += 256)
        atomicAdd(&cnt[row[i] >> 8], 1);
    __syncthreads();
    for (int b = t; b < NBKT_; b += 256) {
        base[b] = (cnt[b] > 0) ? atomicAdd(&bticket[b], cnt[b]) : 0;
        cnt[b] = 0;
    }
    __syncthreads();
    for (int i = i0 + t; i < i0 + CHUNK_; i += 256) {
        const int r = row[i];
        const int b = r >> 8;
        const int k = atomicAdd(&cnt[b], 1);
        stage[base[b] + k] = make_int2(__float_as_int(vals[i]),
                                       col[i] | ((r & 255) << 16));
    }
}

// Phase 2: bucket-local CSR ordering. One block per bucket; reads and writes
// confined to the bucket's contiguous ~32 KB region.
__global__ __launch_bounds__(256) void k_bsort(
        const int* __restrict__ row_ptr, const int2* __restrict__ stage,
        int2* __restrict__ pairs) {
    __shared__ int rp_loc[257];
    __shared__ int c2[256];
    const int b  = blockIdx.x;
    const int t  = threadIdx.x;
    const int r0 = b * 256;
    const int nr = (r0 + 256 <= M_) ? 256 : (M_ - r0);
    if (t < nr) rp_loc[t] = row_ptr[r0 + t];
    if (t == 0) rp_loc[nr] = row_ptr[r0 + nr];   // boundary: ALWAYS loaded
    c2[t] = 0;
    __syncthreads();
    const int base = rp_loc[0];
    const int end  = rp_loc[nr];
    for (int e = base + t; e < end; e += 256) {
        const int2 en = stage[e];
        const int rl = en.y >> 16;
        const int k  = atomicAdd(&c2[rl], 1);
        pairs[rp_loc[rl] + k] = make_int2(en.x, en.y & 0xFFFF);
    }
}

// ---------------------------------------------------------------------------
// bf16 SpMM: Y[r,:] = scale * sum_j v_j * X[c_j,:]  (- prev[r,:] if prev)
// 32 lanes per row (256 B bf16 row), fp32 accumulate, j unrolled x2 for MLP.
__global__ __launch_bounds__(256) void k_spmm_bf16(
        const unsigned short* __restrict__ X, const unsigned short* __restrict__ prev,
        unsigned short* __restrict__ Y, const int* __restrict__ rp,
        const long long* __restrict__ pairs, float scale) {
    const int r = blockIdx.x * RPBLK_ + (threadIdx.x >> 5);
    if (r >= M_) return;
    const int lane = threadIdx.x & 31;
    const size_t off = (size_t)r * ROWB_ + lane * 4;

    const int jb = rp[r], je = rp[r + 1];
    f32x4 a0 = {0.f, 0.f, 0.f, 0.f}, a1 = {0.f, 0.f, 0.f, 0.f};
    int j = jb;
    for (; j + 1 < je; j += 2) {
        const long long p0 = pairs[j], p1 = pairs[j + 1];
        const float v0 = __int_as_float((int)p0);
        const float v1 = __int_as_float((int)p1);
        const int   c0 = (int)(p0 >> 32), c1 = (int)(p1 >> 32);
        const ushort4 u0 = *reinterpret_cast<const ushort4*>(X + (size_t)c0 * ROWB_ + lane * 4);
        const ushort4 u1 = *reinterpret_cast<const ushort4*>(X + (size_t)c1 * ROWB_ + lane * 4);
        const f32x4 x0 = {bf2f(u0.x), bf2f(u0.y), bf2f(u0.z), bf2f(u0.w)};
        const f32x4 x1 = {bf2f(u1.x), bf2f(u1.y), bf2f(u1.z), bf2f(u1.w)};
        a0 += v0 * x0;
        a1 += v1 * x1;
    }
    if (j < je) {
        const long long p0 = pairs[j];
        const float v0 = __int_as_float((int)p0);
        const int   c0 = (int)(p0 >> 32);
        const ushort4 u0 = *reinterpret_cast<const ushort4*>(X + (size_t)c0 * ROWB_ + lane * 4);
        const f32x4 x0 = {bf2f(u0.x), bf2f(u0.y), bf2f(u0.z), bf2f(u0.w)};
        a0 += v0 * x0;
    }
    f32x4 res = scale * (a0 + a1);
    if (prev) {
        const ushort4 pv = *reinterpret_cast<const ushort4*>(prev + off);
        const f32x4 pf = {bf2f(pv.x), bf2f(pv.y), bf2f(pv.z), bf2f(pv.w)};
        res -= pf;
    }
    ushort4 o;
    o.x = f2bf(res.x); o.y = f2bf(res.y); o.z = f2bf(res.z); o.w = f2bf(res.w);
    *reinterpret_cast<ushort4*>(Y + off) = o;
}

// ---------------------------------------------------------------------------
// fused final einsum (bf16 terms): thread = (n, 2 consecutive m), 32 o in regs.
__global__ __launch_bounds__(256, 4) void k_final(
        const unsigned short* __restrict__ T0, const unsigned short* __restrict__ T1,
        const unsigned short* __restrict__ T2, const unsigned short* __restrict__ T3,
        const float* __restrict__ w, const float* __restrict__ b,
        float* __restrict__ out) {
    int t = blockIdx.x * blockDim.x + threadIdx.x;
    if (t >= MTILES_ * N_) return;
    const int n  = t & 7;
    const int m0 = (t >> 3) * MT_;

    float4 acc[MT_][8];
#pragma unroll
    for (int o4 = 0; o4 < 8; ++o4) {
        float4 bv = *reinterpret_cast<const float4*>(b + o4 * 4);
#pragma unroll
        for (int i = 0; i < MT_; ++i) acc[i][o4] = bv;
    }

    const unsigned short* Ts[4] = {T0, T1, T2, T3};
#pragma unroll
    for (int k = 0; k < KCH_; ++k) {
        const unsigned short* tk = Ts[k] + (size_t)m0 * ROWB_ + n;
#pragma unroll
        for (int f = 0; f < FIN_; ++f) {
            const float tv0 = bf2f(tk[f * 8]);
            const float tv1 = bf2f(tk[ROWB_ + f * 8]);
            const float* wr = w + (f * KCH_ + k) * FOUT_;   // uniform
#pragma unroll
            for (int o4 = 0; o4 < 8; ++o4) {
                float4 wv = *reinterpret_cast<const float4*>(wr + o4 * 4);
                acc[0][o4].x += tv0 * wv.x; acc[0][o4].y += tv0 * wv.y;
                acc[0][o4].z += tv0 * wv.z; acc[0][o4].w += tv0 * wv.w;
                acc[1][o4].x += tv1 * wv.x; acc[1][o4].y += tv1 * wv.y;
                acc[1][o4].z += tv1 * wv.z; acc[1][o4].w += tv1 * wv.w;
            }
        }
    }

#pragma unroll
    for (int i = 0; i < MT_; ++i) {
        float* base = out + ((size_t)n * M_ + (m0 + i)) * FOUT_;
#pragma unroll
        for (int o4 = 0; o4 < 8; ++o4)
            *reinterpret_cast<float4*>(base + o4 * 4) = acc[i][o4];
    }
}

// ---------------------------------------------------------------------------
// fallback per-term accumulation (bf16 term)
__global__ __launch_bounds__(256, 4) void k_accum(
        const unsigned short* __restrict__ T, const float* __restrict__ w,
        const float* __restrict__ b, float* __restrict__ out, int k, int init) {
    int t = blockIdx.x * blockDim.x + threadIdx.x;
    if (t >= MTILES_ * N_) return;
    const int n  = t & 7;
    const int m0 = (t >> 3) * MT_;

    float4 acc[MT_][8];
#pragma unroll
    for (int i = 0; i < MT_; ++i) {
        float* base = out + ((size_t)n * M_ + (m0 + i)) * FOUT_;
#pragma unroll
        for (int o4 = 0; o4 < 8; ++o4) {
            if (init) {
                float4 bv = *reinterpret_cast<const float4*>(b + o4 * 4);
                acc[i][o4] = bv;
            } else {
                acc[i][o4] = *reinterpret_cast<const float4*>(base + o4 * 4);
            }
        }
    }
    const unsigned short* tk = T + (size_t)m0 * ROWB_ + n;
#pragma unroll
    for (int f = 0; f < FIN_; ++f) {
        const float tv0 = bf2f(tk[f * 8]);
        const float tv1 = bf2f(tk[ROWB_ + f * 8]);
        const float* wr = w + (f * KCH_ + k) * FOUT_;
#pragma unroll
        for (int o4 = 0; o4 < 8; ++o4) {
            float4 wv = *reinterpret_cast<const float4*>(wr + o4 * 4);
            acc[0][o4].x += tv0 * wv.x; acc[0][o4].y += tv0 * wv.y;
            acc[0][o4].z += tv0 * wv.z; acc[0][o4].w += tv0 * wv.w;
            acc[1][o4].x += tv1 * wv.x; acc[1][o4].y += tv1 * wv.y;
            acc[1][o4].z += tv1 * wv.z; acc[1][o4].w += tv1 * wv.w;
        }
    }
#pragma unroll
    for (int i = 0; i < MT_; ++i) {
        float* base = out + ((size_t)n * M_ + (m0 + i)) * FOUT_;
#pragma unroll
        for (int o4 = 0; o4 < 8; ++o4)
            *reinterpret_cast<float4*>(base + o4 * 4) = acc[i][o4];
    }
}

// ---------------------------------------------------------------------------
extern "C" void kernel_launch(void* const* d_in, const int* in_sizes, int n_in,
                              void* d_out, int out_size, void* d_ws, size_t ws_size,
                              hipStream_t stream) {
    const float* x    = (const float*)d_in[0];
    const float* vals = (const float*)d_in[1];
    const float* w    = (const float*)d_in[2];
    const float* b    = (const float*)d_in[3];
    const int*   row  = (const int*)d_in[4];
    const int*   col  = (const int*)d_in[5];
    float* out = (float*)d_out;

    const size_t tElems = (size_t)M_ * ROWB_;             // 6.4M bf16 per term
    const size_t tBytes = tElems * 2;                     // 12.8 MB
    const size_t csrBytes = (size_t)(M_ + 1) * 4 + (size_t)M_ * 4
                          + 2 * (size_t)NNZ_ * 8 + 4096;  // pairs + stage
    const size_t fusedBytes = 4 * tBytes + csrBytes;      // ~71 MB
    const bool fused = ws_size >= fusedBytes;

    unsigned short* X0 = (unsigned short*)d_ws;
    unsigned short* T1 = X0 + tElems;
    unsigned short* T2 = T1 + tElems;
    unsigned short* T3 = fused ? (T2 + tElems) : T1;      // fallback: in-place
    char* p = (char*)(fused ? (T3 + tElems) : (T2 + tElems));
    int2* pairs   = (int2*)p;              p += (size_t)NNZ_ * 8;
    int2* stage   = (int2*)p;              p += (size_t)NNZ_ * 8;
    int*  row_ptr = (int*)p;               p += (size_t)(M_ + 1) * 4;
    int*  cnt     = (int*)p;               p += (size_t)M_ * 4;
    int*  bsum    = (int*)p;               p += 1024;
    int*  boff    = (int*)p;               p += 1024;
    int*  bticket = (int*)p;

    const int TB = 256;
    dim3 blk(TB);
    dim3 gN((NNZ_ + TB - 1) / TB);                 // per-nnz
    dim3 gX((M_ * ROWB_ + TB - 1) / TB);           // build_x0
    dim3 gS((M_ + RPBLK_ - 1) / RPBLK_);           // spmm: 8 rows per block
    dim3 gF((MTILES_ * N_ + TB - 1) / TB);         // final / accum

    // ---- build CSR row_ptr ----
    hipMemsetAsync(cnt, 0, (size_t)M_ * 4, stream);
    hipLaunchKernelGGL(k_hist,      gN, blk, 0, stream, row, cnt);
    hipLaunchKernelGGL(k_blocksum,  dim3(SCAN_NB), blk, 0, stream, cnt, bsum);
    hipLaunchKernelGGL(k_scan_bsum, dim3(1), blk, 0, stream, bsum, boff);
    hipLaunchKernelGGL(k_emit,      dim3(SCAN_NB), blk, 0, stream, cnt, boff, row_ptr);

    // ---- two-phase bucketed scatter (write-amplification fix) ----
    hipLaunchKernelGGL(k_binit,    dim3(1), blk, 0, stream, row_ptr, bticket);
    hipLaunchKernelGGL(k_bscatter, dim3(BSC_BLOCKS_), blk, 0, stream,
                       vals, row, col, bticket, stage);
    hipLaunchKernelGGL(k_bsort,    dim3(NBKT_), blk, 0, stream, row_ptr, stage, pairs);

    // ---- X0 (bf16) ----
    hipLaunchKernelGGL(k_build_x0, gX, blk, 0, stream, x, X0);

    const long long* pr = (const long long*)pairs;
    if (fused) {
        hipLaunchKernelGGL(k_spmm_bf16, gS, blk, 0, stream, X0, (const unsigned short*)nullptr,
                           T1, row_ptr, pr, 1.0f);
        hipLaunchKernelGGL(k_spmm_bf16, gS, blk, 0, stream, T1, X0, T2, row_ptr, pr, 2.0f);
        hipLaunchKernelGGL(k_spmm_bf16, gS, blk, 0, stream, T2, T1, T3, row_ptr, pr, 2.0f);
        hipLaunchKernelGGL(k_final, gF, blk, 0, stream, X0, T1, T2, T3, w, b, out);
    } else {
        hipLaunchKernelGGL(k_accum, gF, blk, 0, stream, X0, w, b, out, 0, 1);
        hipLaunchKernelGGL(k_spmm_bf16, gS, blk, 0, stream, X0, (const unsigned short*)nullptr,
                           T1, row_ptr, pr, 1.0f);
        hipLaunchKernelGGL(k_accum, gF, blk, 0, stream, T1, w, b, out, 1, 0);
        hipLaunchKernelGGL(k_spmm_bf16, gS, blk, 0, stream, T1, X0, T2, row_ptr, pr, 2.0f);
        hipLaunchKernelGGL(k_accum, gF, blk, 0, stream, T2, w, b, out, 2, 0);
        // T3 overwrites T1 in place: each element read (prev) then written by the
        // same thread -> no cross-thread hazard.
        hipLaunchKernelGGL(k_spmm_bf16, gS, blk, 0, stream, T2, T1, T1, row_ptr, pr, 2.0f);
        hipLaunchKernelGGL(k_accum, gF, blk, 0, stream, T1, w, b, out, 3, 0);
    }
}

// Round 13
// 250.547 us; speedup vs baseline: 3.5469x; 1.0190x over previous
//
#include <hip/hip_runtime.h>

// Problem constants (fixed-shape problem)
constexpr int N_    = 8;
constexpr int M_    = 50000;
constexpr int FIN_  = 16;
constexpr int FOUT_ = 32;
constexpr int KCH_  = 4;
constexpr int NNZ_  = 800000;
constexpr int ROWB_ = 128;                  // bf16 elems per term row (256 B)
constexpr int SCAN_NB = (M_ + 255) / 256;   // 196 scan blocks
constexpr int MT_   = 2;                    // m-values per thread in k_final
constexpr int MTILES_ = M_ / MT_;           // 25000 m-tiles (exact)
constexpr int RPBLK_ = 8;                   // rows per spmm block (256 thr / 32)
constexpr int NBKT_  = (M_ + 255) / 256;    // 196 row-buckets (256 rows each)
constexpr int BSC_BLOCKS_ = 256;            // bucket-scatter blocks
constexpr int CHUNK_ = NNZ_ / BSC_BLOCKS_;  // 3125 nnz per block (exact)

// Term-row internal layout: element c = n*16 + f  (m-row is 256 B contiguous;
// spmm gathers whole rows so the internal order is free — chosen so k_final
// reads 16 consecutive f per (m,n) as two 16 B ushort8 loads).

typedef float f32x4 __attribute__((ext_vector_type(4)));
typedef unsigned short u16x8 __attribute__((ext_vector_type(8)));

__device__ __forceinline__ float bf2f(unsigned short u) {
    return __uint_as_float(((unsigned int)u) << 16);
}
__device__ __forceinline__ unsigned short f2bf(float f) {   // RNE
    unsigned int u = __float_as_uint(f);
    return (unsigned short)((u + 0x7fffu + ((u >> 16) & 1u)) >> 16);
}

// ---------------------------------------------------------------------------
// X0 bf16: X0[m][n*16+f] = x[n][m][f]  (consecutive t -> consecutive x: coalesced)
__global__ void k_build_x0(const float* __restrict__ x, unsigned short* __restrict__ t0) {
    int t = blockIdx.x * blockDim.x + threadIdx.x;
    if (t >= M_ * ROWB_) return;
    int f = t & 15;
    int n = (t >> 4) & 7;
    int m = t >> 7;
    t0[t] = f2bf(x[((size_t)n * M_ + m) * FIN_ + f]);
}

// ---------------------------------------------------------------------------
// CSR row_ptr build (hist + hierarchical scan)
__global__ void k_hist(const int* __restrict__ row, int* __restrict__ cnt) {
    int i = blockIdx.x * blockDim.x + threadIdx.x;
    if (i < NNZ_) atomicAdd(&cnt[row[i]], 1);
}

__global__ void k_blocksum(const int* __restrict__ cnt, int* __restrict__ bsum) {
    __shared__ int s[256];
    int t = threadIdx.x;
    int idx = blockIdx.x * 256 + t;
    s[t] = (idx < M_) ? cnt[idx] : 0;
    __syncthreads();
    for (int off = 128; off > 0; off >>= 1) {
        if (t < off) s[t] += s[t + off];
        __syncthreads();
    }
    if (t == 0) bsum[blockIdx.x] = s[0];
}

__global__ void k_scan_bsum(const int* __restrict__ bsum, int* __restrict__ boff) {
    __shared__ int s[256];
    int t = threadIdx.x;
    int v = (t < SCAN_NB) ? bsum[t] : 0;
    s[t] = v;
    __syncthreads();
    for (int off = 1; off < 256; off <<= 1) {
        int a = (t >= off) ? s[t - off] : 0;
        __syncthreads();
        s[t] += a;
        __syncthreads();
    }
    if (t < SCAN_NB) boff[t] = s[t] - v;   // exclusive
}

__global__ void k_emit(const int* __restrict__ cnt, const int* __restrict__ boff,
                       int* __restrict__ row_ptr) {
    __shared__ int s[256];
    int t = threadIdx.x;
    int idx = blockIdx.x * 256 + t;
    int v = (idx < M_) ? cnt[idx] : 0;
    s[t] = v;
    __syncthreads();
    for (int off = 1; off < 256; off <<= 1) {
        int a = (t >= off) ? s[t - off] : 0;
        __syncthreads();
        s[t] += a;
        __syncthreads();
    }
    if (idx < M_) row_ptr[idx] = boff[blockIdx.x] + s[t] - v;
    if (idx == 0) row_ptr[M_] = NNZ_;
}

// bticket[b] = row_ptr[b*256] (bucket staging base = its CSR region base)
__global__ void k_binit(const int* __restrict__ row_ptr, int* __restrict__ bticket) {
    int b = blockIdx.x * blockDim.x + threadIdx.x;
    if (b < NBKT_) bticket[b] = row_ptr[b * 256];
}

// ---------------------------------------------------------------------------
// Phase 1: bucket scatter (one global atomic per (block,bucket); sequential
// per-bucket writes -> full-line write utilization).
__global__ __launch_bounds__(256) void k_bscatter(
        const float* __restrict__ vals, const int* __restrict__ row,
        const int* __restrict__ col, int* __restrict__ bticket,
        int2* __restrict__ stage) {
    __shared__ int cnt[NBKT_];
    __shared__ int base[NBKT_];
    const int t = threadIdx.x;
    const int i0 = blockIdx.x * CHUNK_;
    for (int b = t; b < NBKT_; b += 256) cnt[b] = 0;
    __syncthreads();
    for (int i = i0 + t; i < i0 + CHUNK_; i += 256)
        atomicAdd(&cnt[row[i] >> 8], 1);
    __syncthreads();
    for (int b = t; b < NBKT_; b += 256) {
        base[b] = (cnt[b] > 0) ? atomicAdd(&bticket[b], cnt[b]) : 0;
        cnt[b] = 0;
    }
    __syncthreads();
    for (int i = i0 + t; i < i0 + CHUNK_; i += 256) {
        const int r = row[i];
        const int b = r >> 8;
        const int k = atomicAdd(&cnt[b], 1);
        stage[base[b] + k] = make_int2(__float_as_int(vals[i]),
                                       col[i] | ((r & 255) << 16));
    }
}

// Phase 2: bucket-local CSR ordering.
__global__ __launch_bounds__(256) void k_bsort(
        const int* __restrict__ row_ptr, const int2* __restrict__ stage,
        int2* __restrict__ pairs) {
    __shared__ int rp_loc[257];
    __shared__ int c2[256];
    const int b  = blockIdx.x;
    const int t  = threadIdx.x;
    const int r0 = b * 256;
    const int nr = (r0 + 256 <= M_) ? 256 : (M_ - r0);
    if (t < nr) rp_loc[t] = row_ptr[r0 + t];
    if (t == 0) rp_loc[nr] = row_ptr[r0 + nr];   // boundary: ALWAYS loaded
    c2[t] = 0;
    __syncthreads();
    const int base = rp_loc[0];
    const int end  = rp_loc[nr];
    for (int e = base + t; e < end; e += 256) {
        const int2 en = stage[e];
        const int rl = en.y >> 16;
        const int k  = atomicAdd(&c2[rl], 1);
        pairs[rp_loc[rl] + k] = make_int2(en.x, en.y & 0xFFFF);
    }
}

// ---------------------------------------------------------------------------
// bf16 SpMM: Y[r,:] = scale * sum_j v_j * X[c_j,:]  (- prev[r,:] if prev)
// 32 lanes per row (256 B bf16 row), fp32 accumulate, j unrolled x2 for MLP.
__global__ __launch_bounds__(256) void k_spmm_bf16(
        const unsigned short* __restrict__ X, const unsigned short* __restrict__ prev,
        unsigned short* __restrict__ Y, const int* __restrict__ rp,
        const long long* __restrict__ pairs, float scale) {
    const int r = blockIdx.x * RPBLK_ + (threadIdx.x >> 5);
    if (r >= M_) return;
    const int lane = threadIdx.x & 31;
    const size_t off = (size_t)r * ROWB_ + lane * 4;

    const int jb = rp[r], je = rp[r + 1];
    f32x4 a0 = {0.f, 0.f, 0.f, 0.f}, a1 = {0.f, 0.f, 0.f, 0.f};
    int j = jb;
    for (; j + 1 < je; j += 2) {
        const long long p0 = pairs[j], p1 = pairs[j + 1];
        const float v0 = __int_as_float((int)p0);
        const float v1 = __int_as_float((int)p1);
        const int   c0 = (int)(p0 >> 32), c1 = (int)(p1 >> 32);
        const ushort4 u0 = *reinterpret_cast<const ushort4*>(X + (size_t)c0 * ROWB_ + lane * 4);
        const ushort4 u1 = *reinterpret_cast<const ushort4*>(X + (size_t)c1 * ROWB_ + lane * 4);
        const f32x4 x0 = {bf2f(u0.x), bf2f(u0.y), bf2f(u0.z), bf2f(u0.w)};
        const f32x4 x1 = {bf2f(u1.x), bf2f(u1.y), bf2f(u1.z), bf2f(u1.w)};
        a0 += v0 * x0;
        a1 += v1 * x1;
    }
    if (j < je) {
        const long long p0 = pairs[j];
        const float v0 = __int_as_float((int)p0);
        const int   c0 = (int)(p0 >> 32);
        const ushort4 u0 = *reinterpret_cast<const ushort4*>(X + (size_t)c0 * ROWB_ + lane * 4);
        const f32x4 x0 = {bf2f(u0.x), bf2f(u0.y), bf2f(u0.z), bf2f(u0.w)};
        a0 += v0 * x0;
    }
    f32x4 res = scale * (a0 + a1);
    if (prev) {
        const ushort4 pv = *reinterpret_cast<const ushort4*>(prev + off);
        const f32x4 pf = {bf2f(pv.x), bf2f(pv.y), bf2f(pv.z), bf2f(pv.w)};
        res -= pf;
    }
    ushort4 o;
    o.x = f2bf(res.x); o.y = f2bf(res.y); o.z = f2bf(res.z); o.w = f2bf(res.w);
    *reinterpret_cast<ushort4*>(Y + off) = o;
}

// ---------------------------------------------------------------------------
// fused final einsum (bf16 terms, [m][n*16+f] layout): thread = (n, 2 m's),
// 32 o in regs; per (k,m): two contiguous 16 B ushort8 loads cover all 16 f.
__global__ __launch_bounds__(256, 4) void k_final(
        const unsigned short* __restrict__ T0, const unsigned short* __restrict__ T1,
        const unsigned short* __restrict__ T2, const unsigned short* __restrict__ T3,
        const float* __restrict__ w, const float* __restrict__ b,
        float* __restrict__ out) {
    int t = blockIdx.x * blockDim.x + threadIdx.x;
    if (t >= MTILES_ * N_) return;
    const int n  = t & 7;
    const int m0 = (t >> 3) * MT_;

    float4 acc[MT_][8];
#pragma unroll
    for (int o4 = 0; o4 < 8; ++o4) {
        float4 bv = *reinterpret_cast<const float4*>(b + o4 * 4);
#pragma unroll
        for (int i = 0; i < MT_; ++i) acc[i][o4] = bv;
    }

    const unsigned short* Ts[4] = {T0, T1, T2, T3};
#pragma unroll
    for (int k = 0; k < KCH_; ++k) {
        const unsigned short* tk = Ts[k] + (size_t)m0 * ROWB_ + n * 16;
        const u16x8 lo0 = *reinterpret_cast<const u16x8*>(tk);
        const u16x8 hi0 = *reinterpret_cast<const u16x8*>(tk + 8);
        const u16x8 lo1 = *reinterpret_cast<const u16x8*>(tk + ROWB_);
        const u16x8 hi1 = *reinterpret_cast<const u16x8*>(tk + ROWB_ + 8);
#pragma unroll
        for (int f = 0; f < FIN_; ++f) {
            const float tv0 = bf2f(f < 8 ? lo0[f] : hi0[f - 8]);
            const float tv1 = bf2f(f < 8 ? lo1[f] : hi1[f - 8]);
            const float* wr = w + (f * KCH_ + k) * FOUT_;   // uniform
#pragma unroll
            for (int o4 = 0; o4 < 8; ++o4) {
                float4 wv = *reinterpret_cast<const float4*>(wr + o4 * 4);
                acc[0][o4].x += tv0 * wv.x; acc[0][o4].y += tv0 * wv.y;
                acc[0][o4].z += tv0 * wv.z; acc[0][o4].w += tv0 * wv.w;
                acc[1][o4].x += tv1 * wv.x; acc[1][o4].y += tv1 * wv.y;
                acc[1][o4].z += tv1 * wv.z; acc[1][o4].w += tv1 * wv.w;
            }
        }
    }

#pragma unroll
    for (int i = 0; i < MT_; ++i) {
        float* base = out + ((size_t)n * M_ + (m0 + i)) * FOUT_;
#pragma unroll
        for (int o4 = 0; o4 < 8; ++o4)
            *reinterpret_cast<float4*>(base + o4 * 4) = acc[i][o4];
    }
}

// ---------------------------------------------------------------------------
// fallback per-term accumulation (bf16 term, [m][n*16+f] layout)
__global__ __launch_bounds__(256, 4) void k_accum(
        const unsigned short* __restrict__ T, const float* __restrict__ w,
        const float* __restrict__ b, float* __restrict__ out, int k, int init) {
    int t = blockIdx.x * blockDim.x + threadIdx.x;
    if (t >= MTILES_ * N_) return;
    const int n  = t & 7;
    const int m0 = (t >> 3) * MT_;

    float4 acc[MT_][8];
#pragma unroll
    for (int i = 0; i < MT_; ++i) {
        float* base = out + ((size_t)n * M_ + (m0 + i)) * FOUT_;
#pragma unroll
        for (int o4 = 0; o4 < 8; ++o4) {
            if (init) {
                float4 bv = *reinterpret_cast<const float4*>(b + o4 * 4);
                acc[i][o4] = bv;
            } else {
                acc[i][o4] = *reinterpret_cast<const float4*>(base + o4 * 4);
            }
        }
    }
    const unsigned short* tk = T + (size_t)m0 * ROWB_ + n * 16;
    const u16x8 lo0 = *reinterpret_cast<const u16x8*>(tk);
    const u16x8 hi0 = *reinterpret_cast<const u16x8*>(tk + 8);
    const u16x8 lo1 = *reinterpret_cast<const u16x8*>(tk + ROWB_);
    const u16x8 hi1 = *reinterpret_cast<const u16x8*>(tk + ROWB_ + 8);
#pragma unroll
    for (int f = 0; f < FIN_; ++f) {
        const float tv0 = bf2f(f < 8 ? lo0[f] : hi0[f - 8]);
        const float tv1 = bf2f(f < 8 ? lo1[f] : hi1[f - 8]);
        const float* wr = w + (f * KCH_ + k) * FOUT_;
#pragma unroll
        for (int o4 = 0; o4 < 8; ++o4) {
            float4 wv = *reinterpret_cast<const float4*>(wr + o4 * 4);
            acc[0][o4].x += tv0 * wv.x; acc[0][o4].y += tv0 * wv.y;
            acc[0][o4].z += tv0 * wv.z; acc[0][o4].w += tv0 * wv.w;
            acc[1][o4].x += tv1 * wv.x; acc[1][o4].y += tv1 * wv.y;
            acc[1][o4].z += tv1 * wv.z; acc[1][o4].w += tv1 * wv.w;
        }
    }
#pragma unroll
    for (int i = 0; i < MT_; ++i) {
        float* base = out + ((size_t)n * M_ + (m0 + i)) * FOUT_;
#pragma unroll
        for (int o4 = 0; o4 < 8; ++o4)
            *reinterpret_cast<float4*>(base + o4 * 4) = acc[i][o4];
    }
}

// ---------------------------------------------------------------------------
extern "C" void kernel_launch(void* const* d_in, const int* in_sizes, int n_in,
                              void* d_out, int out_size, void* d_ws, size_t ws_size,
                              hipStream_t stream) {
    const float* x    = (const float*)d_in[0];
    const float* vals = (const float*)d_in[1];
    const float* w    = (const float*)d_in[2];
    const float* b    = (const float*)d_in[3];
    const int*   row  = (const int*)d_in[4];
    const int*   col  = (const int*)d_in[5];
    float* out = (float*)d_out;

    const size_t tElems = (size_t)M_ * ROWB_;             // 6.4M bf16 per term
    const size_t tBytes = tElems * 2;                     // 12.8 MB
    const size_t csrBytes = (size_t)(M_ + 1) * 4 + (size_t)M_ * 4
                          + 2 * (size_t)NNZ_ * 8 + 4096;  // pairs + stage
    const size_t fusedBytes = 4 * tBytes + csrBytes;      // ~71 MB
    const bool fused = ws_size >= fusedBytes;

    unsigned short* X0 = (unsigned short*)d_ws;
    unsigned short* T1 = X0 + tElems;
    unsigned short* T2 = T1 + tElems;
    unsigned short* T3 = fused ? (T2 + tElems) : T1;      // fallback: in-place
    char* p = (char*)(fused ? (T3 + tElems) : (T2 + tElems));
    int2* pairs   = (int2*)p;              p += (size_t)NNZ_ * 8;
    int2* stage   = (int2*)p;              p += (size_t)NNZ_ * 8;
    int*  row_ptr = (int*)p;               p += (size_t)(M_ + 1) * 4;
    int*  cnt     = (int*)p;               p += (size_t)M_ * 4;
    int*  bsum    = (int*)p;               p += 1024;
    int*  boff    = (int*)p;               p += 1024;
    int*  bticket = (int*)p;

    const int TB = 256;
    dim3 blk(TB);
    dim3 gN((NNZ_ + TB - 1) / TB);                 // per-nnz
    dim3 gX((M_ * ROWB_ + TB - 1) / TB);           // build_x0
    dim3 gS((M_ + RPBLK_ - 1) / RPBLK_);           // spmm: 8 rows per block
    dim3 gF((MTILES_ * N_ + TB - 1) / TB);         // final / accum

    // ---- build CSR row_ptr ----
    hipMemsetAsync(cnt, 0, (size_t)M_ * 4, stream);
    hipLaunchKernelGGL(k_hist,      gN, blk, 0, stream, row, cnt);
    hipLaunchKernelGGL(k_blocksum,  dim3(SCAN_NB), blk, 0, stream, cnt, bsum);
    hipLaunchKernelGGL(k_scan_bsum, dim3(1), blk, 0, stream, bsum, boff);
    hipLaunchKernelGGL(k_emit,      dim3(SCAN_NB), blk, 0, stream, cnt, boff, row_ptr);

    // ---- two-phase bucketed scatter ----
    hipLaunchKernelGGL(k_binit,    dim3(1), blk, 0, stream, row_ptr, bticket);
    hipLaunchKernelGGL(k_bscatter, dim3(BSC_BLOCKS_), blk, 0, stream,
                       vals, row, col, bticket, stage);
    hipLaunchKernelGGL(k_bsort,    dim3(NBKT_), blk, 0, stream, row_ptr, stage, pairs);

    // ---- X0 (bf16) ----
    hipLaunchKernelGGL(k_build_x0, gX, blk, 0, stream, x, X0);

    const long long* pr = (const long long*)pairs;
    if (fused) {
        hipLaunchKernelGGL(k_spmm_bf16, gS, blk, 0, stream, X0, (const unsigned short*)nullptr,
                           T1, row_ptr, pr, 1.0f);
        hipLaunchKernelGGL(k_spmm_bf16, gS, blk, 0, stream, T1, X0, T2, row_ptr, pr, 2.0f);
        hipLaunchKernelGGL(k_spmm_bf16, gS, blk, 0, stream, T2, T1, T3, row_ptr, pr, 2.0f);
        hipLaunchKernelGGL(k_final, gF, blk, 0, stream, X0, T1, T2, T3, w, b, out);
    } else {
        hipLaunchKernelGGL(k_accum, gF, blk, 0, stream, X0, w, b, out, 0, 1);
        hipLaunchKernelGGL(k_spmm_bf16, gS, blk, 0, stream, X0, (const unsigned short*)nullptr,
                           T1, row_ptr, pr, 1.0f);
        hipLaunchKernelGGL(k_accum, gF, blk, 0, stream, T1, w, b, out, 1, 0);
        hipLaunchKernelGGL(k_spmm_bf16, gS, blk, 0, stream, T1, X0, T2, row_ptr, pr, 2.0f);
        hipLaunchKernelGGL(k_accum, gF, blk, 0, stream, T2, w, b, out, 2, 0);
        // T3 overwrites T1 in place: same-thread read-then-write, no hazard.
        hipLaunchKernelGGL(k_spmm_bf16, gS, blk, 0, stream, T2, T1, T1, row_ptr, pr, 2.0f);
        hipLaunchKernelGGL(k_accum, gF, blk, 0, stream, T1, w, b, out, 3, 0);
    }
}

// Round 14
// 247.987 us; speedup vs baseline: 3.5836x; 1.0103x over previous
//
#include <hip/hip_runtime.h>

// Problem constants (fixed-shape problem)
constexpr int N_    = 8;
constexpr int M_    = 50000;
constexpr int FIN_  = 16;
constexpr int FOUT_ = 32;
constexpr int KCH_  = 4;
constexpr int NNZ_  = 800000;
constexpr int ROWB_ = 128;                  // bf16 elems per term row (256 B)
constexpr int SCAN_NB = (M_ + 255) / 256;   // 196 scan blocks
constexpr int RPBLK_ = 8;                   // rows per spmm block (256 thr / 32)
constexpr int NBKT_  = (M_ + 255) / 256;    // 196 row-buckets (256 rows each)
constexpr int BSC_BLOCKS_ = 256;            // bucket-scatter blocks
constexpr int CHUNK_ = NNZ_ / BSC_BLOCKS_;  // 3125 nnz per block (exact)

// Term-row internal layout: element c = n*16 + f  (m-row is 256 B contiguous;
// spmm gathers whole rows so the internal order is free — chosen so k_final
// reads 16 consecutive f per (m,n) as two 16 B ushort8 loads).

typedef float f32x4 __attribute__((ext_vector_type(4)));
typedef unsigned short u16x8 __attribute__((ext_vector_type(8)));

__device__ __forceinline__ float bf2f(unsigned short u) {
    return __uint_as_float(((unsigned int)u) << 16);
}
__device__ __forceinline__ unsigned short f2bf(float f) {   // RNE
    unsigned int u = __float_as_uint(f);
    return (unsigned short)((u + 0x7fffu + ((u >> 16) & 1u)) >> 16);
}

// ---------------------------------------------------------------------------
// X0 bf16: X0[m][n*16+f] = x[n][m][f]  (consecutive t -> consecutive x: coalesced)
__global__ void k_build_x0(const float* __restrict__ x, unsigned short* __restrict__ t0) {
    int t = blockIdx.x * blockDim.x + threadIdx.x;
    if (t >= M_ * ROWB_) return;
    int f = t & 15;
    int n = (t >> 4) & 7;
    int m = t >> 7;
    t0[t] = f2bf(x[((size_t)n * M_ + m) * FIN_ + f]);
}

// ---------------------------------------------------------------------------
// CSR row_ptr build (hist + hierarchical scan)
__global__ void k_hist(const int* __restrict__ row, int* __restrict__ cnt) {
    int i = blockIdx.x * blockDim.x + threadIdx.x;
    if (i < NNZ_) atomicAdd(&cnt[row[i]], 1);
}

__global__ void k_blocksum(const int* __restrict__ cnt, int* __restrict__ bsum) {
    __shared__ int s[256];
    int t = threadIdx.x;
    int idx = blockIdx.x * 256 + t;
    s[t] = (idx < M_) ? cnt[idx] : 0;
    __syncthreads();
    for (int off = 128; off > 0; off >>= 1) {
        if (t < off) s[t] += s[t + off];
        __syncthreads();
    }
    if (t == 0) bsum[blockIdx.x] = s[0];
}

__global__ void k_scan_bsum(const int* __restrict__ bsum, int* __restrict__ boff) {
    __shared__ int s[256];
    int t = threadIdx.x;
    int v = (t < SCAN_NB) ? bsum[t] : 0;
    s[t] = v;
    __syncthreads();
    for (int off = 1; off < 256; off <<= 1) {
        int a = (t >= off) ? s[t - off] : 0;
        __syncthreads();
        s[t] += a;
        __syncthreads();
    }
    if (t < SCAN_NB) boff[t] = s[t] - v;   // exclusive
}

__global__ void k_emit(const int* __restrict__ cnt, const int* __restrict__ boff,
                       int* __restrict__ row_ptr) {
    __shared__ int s[256];
    int t = threadIdx.x;
    int idx = blockIdx.x * 256 + t;
    int v = (idx < M_) ? cnt[idx] : 0;
    s[t] = v;
    __syncthreads();
    for (int off = 1; off < 256; off <<= 1) {
        int a = (t >= off) ? s[t - off] : 0;
        __syncthreads();
        s[t] += a;
        __syncthreads();
    }
    if (idx < M_) row_ptr[idx] = boff[blockIdx.x] + s[t] - v;
    if (idx == 0) row_ptr[M_] = NNZ_;
}

// bticket[b] = row_ptr[b*256] (bucket staging base = its CSR region base)
__global__ void k_binit(const int* __restrict__ row_ptr, int* __restrict__ bticket) {
    int b = blockIdx.x * blockDim.x + threadIdx.x;
    if (b < NBKT_) bticket[b] = row_ptr[b * 256];
}

// ---------------------------------------------------------------------------
// Phase 1: bucket scatter (one global atomic per (block,bucket); sequential
// per-bucket writes -> full-line write utilization).
__global__ __launch_bounds__(256) void k_bscatter(
        const float* __restrict__ vals, const int* __restrict__ row,
        const int* __restrict__ col, int* __restrict__ bticket,
        int2* __restrict__ stage) {
    __shared__ int cnt[NBKT_];
    __shared__ int base[NBKT_];
    const int t = threadIdx.x;
    const int i0 = blockIdx.x * CHUNK_;
    for (int b = t; b < NBKT_; b += 256) cnt[b] = 0;
    __syncthreads();
    for (int i = i0 + t; i < i0 + CHUNK_; i += 256)
        atomicAdd(&cnt[row[i] >> 8], 1);
    __syncthreads();
    for (int b = t; b < NBKT_; b += 256) {
        base[b] = (cnt[b] > 0) ? atomicAdd(&bticket[b], cnt[b]) : 0;
        cnt[b] = 0;
    }
    __syncthreads();
    for (int i = i0 + t; i < i0 + CHUNK_; i += 256) {
        const int r = row[i];
        const int b = r >> 8;
        const int k = atomicAdd(&cnt[b], 1);
        stage[base[b] + k] = make_int2(__float_as_int(vals[i]),
                                       col[i] | ((r & 255) << 16));
    }
}

// Phase 2: bucket-local CSR ordering.
__global__ __launch_bounds__(256) void k_bsort(
        const int* __restrict__ row_ptr, const int2* __restrict__ stage,
        int2* __restrict__ pairs) {
    __shared__ int rp_loc[257];
    __shared__ int c2[256];
    const int b  = blockIdx.x;
    const int t  = threadIdx.x;
    const int r0 = b * 256;
    const int nr = (r0 + 256 <= M_) ? 256 : (M_ - r0);
    if (t < nr) rp_loc[t] = row_ptr[r0 + t];
    if (t == 0) rp_loc[nr] = row_ptr[r0 + nr];   // boundary: ALWAYS loaded
    c2[t] = 0;
    __syncthreads();
    const int base = rp_loc[0];
    const int end  = rp_loc[nr];
    for (int e = base + t; e < end; e += 256) {
        const int2 en = stage[e];
        const int rl = en.y >> 16;
        const int k  = atomicAdd(&c2[rl], 1);
        pairs[rp_loc[rl] + k] = make_int2(en.x, en.y & 0xFFFF);
    }
}

// ---------------------------------------------------------------------------
// bf16 SpMM: Y[r,:] = scale * sum_j v_j * X[c_j,:]  (- prev[r,:] if prev)
// 32 lanes per row (256 B bf16 row), fp32 accumulate, j unrolled x2 for MLP.
__global__ __launch_bounds__(256) void k_spmm_bf16(
        const unsigned short* __restrict__ X, const unsigned short* __restrict__ prev,
        unsigned short* __restrict__ Y, const int* __restrict__ rp,
        const long long* __restrict__ pairs, float scale) {
    const int r = blockIdx.x * RPBLK_ + (threadIdx.x >> 5);
    if (r >= M_) return;
    const int lane = threadIdx.x & 31;
    const size_t off = (size_t)r * ROWB_ + lane * 4;

    const int jb = rp[r], je = rp[r + 1];
    f32x4 a0 = {0.f, 0.f, 0.f, 0.f}, a1 = {0.f, 0.f, 0.f, 0.f};
    int j = jb;
    for (; j + 1 < je; j += 2) {
        const long long p0 = pairs[j], p1 = pairs[j + 1];
        const float v0 = __int_as_float((int)p0);
        const float v1 = __int_as_float((int)p1);
        const int   c0 = (int)(p0 >> 32), c1 = (int)(p1 >> 32);
        const ushort4 u0 = *reinterpret_cast<const ushort4*>(X + (size_t)c0 * ROWB_ + lane * 4);
        const ushort4 u1 = *reinterpret_cast<const ushort4*>(X + (size_t)c1 * ROWB_ + lane * 4);
        const f32x4 x0 = {bf2f(u0.x), bf2f(u0.y), bf2f(u0.z), bf2f(u0.w)};
        const f32x4 x1 = {bf2f(u1.x), bf2f(u1.y), bf2f(u1.z), bf2f(u1.w)};
        a0 += v0 * x0;
        a1 += v1 * x1;
    }
    if (j < je) {
        const long long p0 = pairs[j];
        const float v0 = __int_as_float((int)p0);
        const int   c0 = (int)(p0 >> 32);
        const ushort4 u0 = *reinterpret_cast<const ushort4*>(X + (size_t)c0 * ROWB_ + lane * 4);
        const f32x4 x0 = {bf2f(u0.x), bf2f(u0.y), bf2f(u0.z), bf2f(u0.w)};
        a0 += v0 * x0;
    }
    f32x4 res = scale * (a0 + a1);
    if (prev) {
        const ushort4 pv = *reinterpret_cast<const ushort4*>(prev + off);
        const f32x4 pf = {bf2f(pv.x), bf2f(pv.y), bf2f(pv.z), bf2f(pv.w)};
        res -= pf;
    }
    ushort4 o;
    o.x = f2bf(res.x); o.y = f2bf(res.y); o.z = f2bf(res.z); o.w = f2bf(res.w);
    *reinterpret_cast<ushort4*>(Y + off) = o;
}

// ---------------------------------------------------------------------------
// fused final einsum (bf16 terms, [m][n*16+f] layout).
// Thread = one (n,m); acc float4[8] = 32 VGPR; w staged in LDS (8 KB) and read
// as uniform-address ds_read_b128 broadcasts. Grid 1563 blocks (~6/CU).
__global__ __launch_bounds__(256) void k_final(
        const unsigned short* __restrict__ T0, const unsigned short* __restrict__ T1,
        const unsigned short* __restrict__ T2, const unsigned short* __restrict__ T3,
        const float* __restrict__ w, const float* __restrict__ b,
        float* __restrict__ out) {
    __shared__ float lw[FIN_ * KCH_ * FOUT_];   // 2048 floats = 8 KB
    {
        const float4* ws = reinterpret_cast<const float4*>(w);
        float4* ld = reinterpret_cast<float4*>(lw);
        ld[threadIdx.x]       = ws[threadIdx.x];
        ld[threadIdx.x + 256] = ws[threadIdx.x + 256];
    }
    __syncthreads();

    int t = blockIdx.x * blockDim.x + threadIdx.x;
    if (t >= M_ * N_) return;
    const int n = t & 7;
    const int m = t >> 3;

    float4 acc[8];
#pragma unroll
    for (int o4 = 0; o4 < 8; ++o4)
        acc[o4] = *reinterpret_cast<const float4*>(b + o4 * 4);

    const unsigned short* Ts[4] = {T0, T1, T2, T3};
#pragma unroll
    for (int k = 0; k < KCH_; ++k) {
        const unsigned short* tk = Ts[k] + (size_t)m * ROWB_ + n * 16;
        const u16x8 lo = *reinterpret_cast<const u16x8*>(tk);
        const u16x8 hi = *reinterpret_cast<const u16x8*>(tk + 8);
#pragma unroll
        for (int f = 0; f < FIN_; ++f) {
            const float tv = bf2f(f < 8 ? lo[f] : hi[f - 8]);
            const float* wr = &lw[(f * KCH_ + k) * FOUT_];   // uniform LDS addr
#pragma unroll
            for (int o4 = 0; o4 < 8; ++o4) {
                float4 wv = *reinterpret_cast<const float4*>(wr + o4 * 4);
                acc[o4].x += tv * wv.x; acc[o4].y += tv * wv.y;
                acc[o4].z += tv * wv.z; acc[o4].w += tv * wv.w;
            }
        }
    }

    float* base = out + ((size_t)n * M_ + m) * FOUT_;
#pragma unroll
    for (int o4 = 0; o4 < 8; ++o4)
        *reinterpret_cast<float4*>(base + o4 * 4) = acc[o4];
}

// ---------------------------------------------------------------------------
// fallback per-term accumulation (bf16 term, [m][n*16+f] layout)
__global__ __launch_bounds__(256) void k_accum(
        const unsigned short* __restrict__ T, const float* __restrict__ w,
        const float* __restrict__ b, float* __restrict__ out, int k, int init) {
    int t = blockIdx.x * blockDim.x + threadIdx.x;
    if (t >= M_ * N_) return;
    const int n = t & 7;
    const int m = t >> 3;

    float* base = out + ((size_t)n * M_ + m) * FOUT_;
    float4 acc[8];
#pragma unroll
    for (int o4 = 0; o4 < 8; ++o4)
        acc[o4] = init ? *reinterpret_cast<const float4*>(b + o4 * 4)
                       : *reinterpret_cast<const float4*>(base + o4 * 4);

    const unsigned short* tk = T + (size_t)m * ROWB_ + n * 16;
    const u16x8 lo = *reinterpret_cast<const u16x8*>(tk);
    const u16x8 hi = *reinterpret_cast<const u16x8*>(tk + 8);
#pragma unroll
    for (int f = 0; f < FIN_; ++f) {
        const float tv = bf2f(f < 8 ? lo[f] : hi[f - 8]);
        const float* wr = w + (f * KCH_ + k) * FOUT_;
#pragma unroll
        for (int o4 = 0; o4 < 8; ++o4) {
            float4 wv = *reinterpret_cast<const float4*>(wr + o4 * 4);
            acc[o4].x += tv * wv.x; acc[o4].y += tv * wv.y;
            acc[o4].z += tv * wv.z; acc[o4].w += tv * wv.w;
        }
    }
#pragma unroll
    for (int o4 = 0; o4 < 8; ++o4)
        *reinterpret_cast<float4*>(base + o4 * 4) = acc[o4];
}

// ---------------------------------------------------------------------------
extern "C" void kernel_launch(void* const* d_in, const int* in_sizes, int n_in,
                              void* d_out, int out_size, void* d_ws, size_t ws_size,
                              hipStream_t stream) {
    const float* x    = (const float*)d_in[0];
    const float* vals = (const float*)d_in[1];
    const float* w    = (const float*)d_in[2];
    const float* b    = (const float*)d_in[3];
    const int*   row  = (const int*)d_in[4];
    const int*   col  = (const int*)d_in[5];
    float* out = (float*)d_out;

    const size_t tElems = (size_t)M_ * ROWB_;             // 6.4M bf16 per term
    const size_t tBytes = tElems * 2;                     // 12.8 MB
    const size_t csrBytes = (size_t)(M_ + 1) * 4 + (size_t)M_ * 4
                          + 2 * (size_t)NNZ_ * 8 + 4096;  // pairs + stage
    const size_t fusedBytes = 4 * tBytes + csrBytes;      // ~71 MB
    const bool fused = ws_size >= fusedBytes;

    unsigned short* X0 = (unsigned short*)d_ws;
    unsigned short* T1 = X0 + tElems;
    unsigned short* T2 = T1 + tElems;
    unsigned short* T3 = fused ? (T2 + tElems) : T1;      // fallback: in-place
    char* p = (char*)(fused ? (T3 + tElems) : (T2 + tElems));
    int2* pairs   = (int2*)p;              p += (size_t)NNZ_ * 8;
    int2* stage   = (int2*)p;              p += (size_t)NNZ_ * 8;
    int*  row_ptr = (int*)p;               p += (size_t)(M_ + 1) * 4;
    int*  cnt     = (int*)p;               p += (size_t)M_ * 4;
    int*  bsum    = (int*)p;               p += 1024;
    int*  boff    = (int*)p;               p += 1024;
    int*  bticket = (int*)p;

    const int TB = 256;
    dim3 blk(TB);
    dim3 gN((NNZ_ + TB - 1) / TB);                 // per-nnz
    dim3 gX((M_ * ROWB_ + TB - 1) / TB);           // build_x0
    dim3 gS((M_ + RPBLK_ - 1) / RPBLK_);           // spmm: 8 rows per block
    dim3 gF((M_ * N_ + TB - 1) / TB);              // final / accum: thread per (n,m)

    // ---- build CSR row_ptr ----
    hipMemsetAsync(cnt, 0, (size_t)M_ * 4, stream);
    hipLaunchKernelGGL(k_hist,      gN, blk, 0, stream, row, cnt);
    hipLaunchKernelGGL(k_blocksum,  dim3(SCAN_NB), blk, 0, stream, cnt, bsum);
    hipLaunchKernelGGL(k_scan_bsum, dim3(1), blk, 0, stream, bsum, boff);
    hipLaunchKernelGGL(k_emit,      dim3(SCAN_NB), blk, 0, stream, cnt, boff, row_ptr);

    // ---- two-phase bucketed scatter ----
    hipLaunchKernelGGL(k_binit,    dim3(1), blk, 0, stream, row_ptr, bticket);
    hipLaunchKernelGGL(k_bscatter, dim3(BSC_BLOCKS_), blk, 0, stream,
                       vals, row, col, bticket, stage);
    hipLaunchKernelGGL(k_bsort,    dim3(NBKT_), blk, 0, stream, row_ptr, stage, pairs);

    // ---- X0 (bf16) ----
    hipLaunchKernelGGL(k_build_x0, gX, blk, 0, stream, x, X0);

    const long long* pr = (const long long*)pairs;
    if (fused) {
        hipLaunchKernelGGL(k_spmm_bf16, gS, blk, 0, stream, X0, (const unsigned short*)nullptr,
                           T1, row_ptr, pr, 1.0f);
        hipLaunchKernelGGL(k_spmm_bf16, gS, blk, 0, stream, T1, X0, T2, row_ptr, pr, 2.0f);
        hipLaunchKernelGGL(k_spmm_bf16, gS, blk, 0, stream, T2, T1, T3, row_ptr, pr, 2.0f);
        hipLaunchKernelGGL(k_final, gF, blk, 0, stream, X0, T1, T2, T3, w, b, out);
    } else {
        hipLaunchKernelGGL(k_accum, gF, blk, 0, stream, X0, w, b, out, 0, 1);
        hipLaunchKernelGGL(k_spmm_bf16, gS, blk, 0, stream, X0, (const unsigned short*)nullptr,
                           T1, row_ptr, pr, 1.0f);
        hipLaunchKernelGGL(k_accum, gF, blk, 0, stream, T1, w, b, out, 1, 0);
        hipLaunchKernelGGL(k_spmm_bf16, gS, blk, 0, stream, T1, X0, T2, row_ptr, pr, 2.0f);
        hipLaunchKernelGGL(k_accum, gF, blk, 0, stream, T2, w, b, out, 2, 0);
        // T3 overwrites T1 in place: same-thread read-then-write, no hazard.
        hipLaunchKernelGGL(k_spmm_bf16, gS, blk, 0, stream, T2, T1, T1, row_ptr, pr, 2.0f);
        hipLaunchKernelGGL(k_accum, gF, blk, 0, stream, T1, w, b, out, 3, 0);
    }
}

// Round 15
// 226.396 us; speedup vs baseline: 3.9253x; 1.0954x over previous
//
#include <hip/hip_runtime.h>

// Problem constants (fixed-shape problem)
constexpr int N_    = 8;
constexpr int M_    = 50000;
constexpr int FIN_  = 16;
constexpr int FOUT_ = 32;
constexpr int KCH_  = 4;
constexpr int NNZ_  = 800000;
constexpr int ROWB_ = 128;                  // bf16 elems per term row (256 B)
constexpr int SCAN_NB = (M_ + 255) / 256;   // 196 scan blocks
constexpr int RPBLK_ = 8;                   // rows per spmm block (256 thr / 32)
constexpr int NBKT_  = (M_ + 255) / 256;    // 196 row-buckets (256 rows each)
constexpr int BSC_BLOCKS_ = 256;            // bucket-scatter blocks
constexpr int CHUNK_ = NNZ_ / BSC_BLOCKS_;  // 3125 nnz per block (exact)
constexpr int NTILE_ = M_ / 2;              // 25000 2-m tiles (exact)

// Term-row internal layout: element c = n*16 + f  (m-row is 256 B contiguous;
// spmm gathers whole rows so the internal order is free — chosen so both the
// MFMA A-fragment and k_accum read contiguous 16 B per (m,n,k)).

typedef float f32x4 __attribute__((ext_vector_type(4)));
typedef unsigned short u16x8 __attribute__((ext_vector_type(8)));
typedef short bf16x8 __attribute__((ext_vector_type(8)));   // MFMA A/B fragment
typedef float f32x4v __attribute__((ext_vector_type(4)));   // MFMA C/D fragment

__device__ __forceinline__ float bf2f(unsigned short u) {
    return __uint_as_float(((unsigned int)u) << 16);
}
__device__ __forceinline__ unsigned short f2bf(float f) {   // RNE
    unsigned int u = __float_as_uint(f);
    return (unsigned short)((u + 0x7fffu + ((u >> 16) & 1u)) >> 16);
}

// ---------------------------------------------------------------------------
// X0 bf16: X0[m][n*16+f] = x[n][m][f]  (consecutive t -> consecutive x: coalesced)
__global__ void k_build_x0(const float* __restrict__ x, unsigned short* __restrict__ t0) {
    int t = blockIdx.x * blockDim.x + threadIdx.x;
    if (t >= M_ * ROWB_) return;
    int f = t & 15;
    int n = (t >> 4) & 7;
    int m = t >> 7;
    t0[t] = f2bf(x[((size_t)n * M_ + m) * FIN_ + f]);
}

// ---------------------------------------------------------------------------
// CSR row_ptr build (hist + hierarchical scan)
__global__ void k_hist(const int* __restrict__ row, int* __restrict__ cnt) {
    int i = blockIdx.x * blockDim.x + threadIdx.x;
    if (i < NNZ_) atomicAdd(&cnt[row[i]], 1);
}

__global__ void k_blocksum(const int* __restrict__ cnt, int* __restrict__ bsum) {
    __shared__ int s[256];
    int t = threadIdx.x;
    int idx = blockIdx.x * 256 + t;
    s[t] = (idx < M_) ? cnt[idx] : 0;
    __syncthreads();
    for (int off = 128; off > 0; off >>= 1) {
        if (t < off) s[t] += s[t + off];
        __syncthreads();
    }
    if (t == 0) bsum[blockIdx.x] = s[0];
}

__global__ void k_scan_bsum(const int* __restrict__ bsum, int* __restrict__ boff) {
    __shared__ int s[256];
    int t = threadIdx.x;
    int v = (t < SCAN_NB) ? bsum[t] : 0;
    s[t] = v;
    __syncthreads();
    for (int off = 1; off < 256; off <<= 1) {
        int a = (t >= off) ? s[t - off] : 0;
        __syncthreads();
        s[t] += a;
        __syncthreads();
    }
    if (t < SCAN_NB) boff[t] = s[t] - v;   // exclusive
}

__global__ void k_emit(const int* __restrict__ cnt, const int* __restrict__ boff,
                       int* __restrict__ row_ptr) {
    __shared__ int s[256];
    int t = threadIdx.x;
    int idx = blockIdx.x * 256 + t;
    int v = (idx < M_) ? cnt[idx] : 0;
    s[t] = v;
    __syncthreads();
    for (int off = 1; off < 256; off <<= 1) {
        int a = (t >= off) ? s[t - off] : 0;
        __syncthreads();
        s[t] += a;
        __syncthreads();
    }
    if (idx < M_) row_ptr[idx] = boff[blockIdx.x] + s[t] - v;
    if (idx == 0) row_ptr[M_] = NNZ_;
}

// bticket[b] = row_ptr[b*256] (bucket staging base = its CSR region base)
__global__ void k_binit(const int* __restrict__ row_ptr, int* __restrict__ bticket) {
    int b = blockIdx.x * blockDim.x + threadIdx.x;
    if (b < NBKT_) bticket[b] = row_ptr[b * 256];
}

// ---------------------------------------------------------------------------
// Phase 1: bucket scatter (one global atomic per (block,bucket); sequential
// per-bucket writes -> full-line write utilization).
__global__ __launch_bounds__(256) void k_bscatter(
        const float* __restrict__ vals, const int* __restrict__ row,
        const int* __restrict__ col, int* __restrict__ bticket,
        int2* __restrict__ stage) {
    __shared__ int cnt[NBKT_];
    __shared__ int base[NBKT_];
    const int t = threadIdx.x;
    const int i0 = blockIdx.x * CHUNK_;
    for (int b = t; b < NBKT_; b += 256) cnt[b] = 0;
    __syncthreads();
    for (int i = i0 + t; i < i0 + CHUNK_; i += 256)
        atomicAdd(&cnt[row[i] >> 8], 1);
    __syncthreads();
    for (int b = t; b < NBKT_; b += 256) {
        base[b] = (cnt[b] > 0) ? atomicAdd(&bticket[b], cnt[b]) : 0;
        cnt[b] = 0;
    }
    __syncthreads();
    for (int i = i0 + t; i < i0 + CHUNK_; i += 256) {
        const int r = row[i];
        const int b = r >> 8;
        const int k = atomicAdd(&cnt[b], 1);
        stage[base[b] + k] = make_int2(__float_as_int(vals[i]),
                                       col[i] | ((r & 255) << 16));
    }
}

// Phase 2: bucket-local CSR ordering.
__global__ __launch_bounds__(256) void k_bsort(
        const int* __restrict__ row_ptr, const int2* __restrict__ stage,
        int2* __restrict__ pairs) {
    __shared__ int rp_loc[257];
    __shared__ int c2[256];
    const int b  = blockIdx.x;
    const int t  = threadIdx.x;
    const int r0 = b * 256;
    const int nr = (r0 + 256 <= M_) ? 256 : (M_ - r0);
    if (t < nr) rp_loc[t] = row_ptr[r0 + t];
    if (t == 0) rp_loc[nr] = row_ptr[r0 + nr];   // boundary: ALWAYS loaded
    c2[t] = 0;
    __syncthreads();
    const int base = rp_loc[0];
    const int end  = rp_loc[nr];
    for (int e = base + t; e < end; e += 256) {
        const int2 en = stage[e];
        const int rl = en.y >> 16;
        const int k  = atomicAdd(&c2[rl], 1);
        pairs[rp_loc[rl] + k] = make_int2(en.x, en.y & 0xFFFF);
    }
}

// ---------------------------------------------------------------------------
// bf16 SpMM: Y[r,:] = scale * sum_j v_j * X[c_j,:]  (- prev[r,:] if prev)
// 32 lanes per row (256 B bf16 row), fp32 accumulate, j unrolled x2 for MLP.
__global__ __launch_bounds__(256) void k_spmm_bf16(
        const unsigned short* __restrict__ X, const unsigned short* __restrict__ prev,
        unsigned short* __restrict__ Y, const int* __restrict__ rp,
        const long long* __restrict__ pairs, float scale) {
    const int r = blockIdx.x * RPBLK_ + (threadIdx.x >> 5);
    if (r >= M_) return;
    const int lane = threadIdx.x & 31;
    const size_t off = (size_t)r * ROWB_ + lane * 4;

    const int jb = rp[r], je = rp[r + 1];
    f32x4 a0 = {0.f, 0.f, 0.f, 0.f}, a1 = {0.f, 0.f, 0.f, 0.f};
    int j = jb;
    for (; j + 1 < je; j += 2) {
        const long long p0 = pairs[j], p1 = pairs[j + 1];
        const float v0 = __int_as_float((int)p0);
        const float v1 = __int_as_float((int)p1);
        const int   c0 = (int)(p0 >> 32), c1 = (int)(p1 >> 32);
        const ushort4 u0 = *reinterpret_cast<const ushort4*>(X + (size_t)c0 * ROWB_ + lane * 4);
        const ushort4 u1 = *reinterpret_cast<const ushort4*>(X + (size_t)c1 * ROWB_ + lane * 4);
        const f32x4 x0 = {bf2f(u0.x), bf2f(u0.y), bf2f(u0.z), bf2f(u0.w)};
        const f32x4 x1 = {bf2f(u1.x), bf2f(u1.y), bf2f(u1.z), bf2f(u1.w)};
        a0 += v0 * x0;
        a1 += v1 * x1;
    }
    if (j < je) {
        const long long p0 = pairs[j];
        const float v0 = __int_as_float((int)p0);
        const int   c0 = (int)(p0 >> 32);
        const ushort4 u0 = *reinterpret_cast<const ushort4*>(X + (size_t)c0 * ROWB_ + lane * 4);
        const f32x4 x0 = {bf2f(u0.x), bf2f(u0.y), bf2f(u0.z), bf2f(u0.w)};
        a0 += v0 * x0;
    }
    f32x4 res = scale * (a0 + a1);
    if (prev) {
        const ushort4 pv = *reinterpret_cast<const ushort4*>(prev + off);
        const f32x4 pf = {bf2f(pv.x), bf2f(pv.y), bf2f(pv.z), bf2f(pv.w)};
        res -= pf;
    }
    ushort4 o;
    o.x = f2bf(res.x); o.y = f2bf(res.y); o.z = f2bf(res.z); o.w = f2bf(res.w);
    *reinterpret_cast<ushort4*>(Y + off) = o;
}

// ---------------------------------------------------------------------------
// MFMA final einsum. Per 2-m tile: out[16 rows = 2m x 8n][32 o] =
//   sum_{K=64 (f,kcheb)} A[row][K] * B[K][o] + bias,
// as 2 chained mfma_f32_16x16x32_bf16 per o-half (K split 0..31 -> T0/T1,
// 32..63 -> T2/T3). A-frag: lane l&15 = row (mloc = (l&15)>>3, n = l&7),
// K-group (l>>4)*8+j -> one contiguous 16 B term load. B-frag: w bf16 held in
// 16 VGPRs for the whole kernel (consistent K labels A<->B make the result
// invariant to the HW's internal K permutation). C/D: col=l&15,
// row=(l>>4)*4+reg [verified mapping]. Bias folded into acc init. No LDS.
__global__ __launch_bounds__(256) void k_final(
        const unsigned short* __restrict__ T0, const unsigned short* __restrict__ T1,
        const unsigned short* __restrict__ T2, const unsigned short* __restrict__ T3,
        const float* __restrict__ w, const float* __restrict__ b,
        float* __restrict__ out) {
    const int lane = threadIdx.x & 63;
    const int lg   = lane >> 4;          // 0..3 (K-group / D-row group)
    const int ll   = lane & 15;          // A row / B col / D col
    const int wid    = (blockIdx.x * blockDim.x + threadIdx.x) >> 6;
    const int nwaves = (gridDim.x * blockDim.x) >> 6;

    // B fragments: mm = which MFMA (0: kcheb 0/1, 1: kcheb 2/3), oh = o-half.
    bf16x8 bfrag[2][2];
#pragma unroll
    for (int mm = 0; mm < 2; ++mm)
#pragma unroll
        for (int oh = 0; oh < 2; ++oh)
#pragma unroll
            for (int j = 0; j < 8; ++j) {
                const int k  = lg * 8 + j;            // 0..31
                const int kc = mm * 2 + (k >> 4);     // cheb index
                const int f  = k & 15;
                bfrag[mm][oh][j] =
                    (short)f2bf(w[(f * KCH_ + kc) * FOUT_ + oh * 16 + ll]);
            }
    const float bias0 = b[ll], bias1 = b[16 + ll];

    // A-source: MFMA0 reads T0 (lg 0,1) / T1 (lg 2,3); MFMA1 reads T2/T3.
    const unsigned short* TA = (lg < 2) ? T0 : T1;
    const unsigned short* TB = (lg < 2) ? T2 : T3;
    const int mloc = ll >> 3;
    const int n    = ll & 7;
    const int fofs = (lg & 1) * 8;
    const size_t eoff = (size_t)n * 16 + fofs;

    for (int tile = wid; tile < NTILE_; tile += nwaves) {
        const int m0 = tile * 2;
        const size_t rowoff = (size_t)(m0 + mloc) * ROWB_ + eoff;
        const bf16x8 a01 = *reinterpret_cast<const bf16x8*>(TA + rowoff);
        const bf16x8 a23 = *reinterpret_cast<const bf16x8*>(TB + rowoff);

        f32x4v acc0 = {bias0, bias0, bias0, bias0};
        f32x4v acc1 = {bias1, bias1, bias1, bias1};
        acc0 = __builtin_amdgcn_mfma_f32_16x16x32_bf16(a01, bfrag[0][0], acc0, 0, 0, 0);
        acc0 = __builtin_amdgcn_mfma_f32_16x16x32_bf16(a23, bfrag[1][0], acc0, 0, 0, 0);
        acc1 = __builtin_amdgcn_mfma_f32_16x16x32_bf16(a01, bfrag[0][1], acc1, 0, 0, 0);
        acc1 = __builtin_amdgcn_mfma_f32_16x16x32_bf16(a23, bfrag[1][1], acc1, 0, 0, 0);

#pragma unroll
        for (int r = 0; r < 4; ++r) {
            const int drow = lg * 4 + r;              // 0..15
            const int dm   = drow >> 3;
            const int dn   = drow & 7;
            float* base = out + ((size_t)dn * M_ + m0 + dm) * FOUT_;
            base[ll]      = acc0[r];
            base[16 + ll] = acc1[r];
        }
    }
}

// ---------------------------------------------------------------------------
// fallback per-term accumulation (bf16 term, [m][n*16+f] layout)
__global__ __launch_bounds__(256) void k_accum(
        const unsigned short* __restrict__ T, const float* __restrict__ w,
        const float* __restrict__ b, float* __restrict__ out, int k, int init) {
    int t = blockIdx.x * blockDim.x + threadIdx.x;
    if (t >= M_ * N_) return;
    const int n = t & 7;
    const int m = t >> 3;

    float* base = out + ((size_t)n * M_ + m) * FOUT_;
    float4 acc[8];
#pragma unroll
    for (int o4 = 0; o4 < 8; ++o4)
        acc[o4] = init ? *reinterpret_cast<const float4*>(b + o4 * 4)
                       : *reinterpret_cast<const float4*>(base + o4 * 4);

    const unsigned short* tk = T + (size_t)m * ROWB_ + n * 16;
    const u16x8 lo = *reinterpret_cast<const u16x8*>(tk);
    const u16x8 hi = *reinterpret_cast<const u16x8*>(tk + 8);
#pragma unroll
    for (int f = 0; f < FIN_; ++f) {
        const float tv = bf2f(f < 8 ? lo[f] : hi[f - 8]);
        const float* wr = w + (f * KCH_ + k) * FOUT_;
#pragma unroll
        for (int o4 = 0; o4 < 8; ++o4) {
            float4 wv = *reinterpret_cast<const float4*>(wr + o4 * 4);
            acc[o4].x += tv * wv.x; acc[o4].y += tv * wv.y;
            acc[o4].z += tv * wv.z; acc[o4].w += tv * wv.w;
        }
    }
#pragma unroll
    for (int o4 = 0; o4 < 8; ++o4)
        *reinterpret_cast<float4*>(base + o4 * 4) = acc[o4];
}

// ---------------------------------------------------------------------------
extern "C" void kernel_launch(void* const* d_in, const int* in_sizes, int n_in,
                              void* d_out, int out_size, void* d_ws, size_t ws_size,
                              hipStream_t stream) {
    const float* x    = (const float*)d_in[0];
    const float* vals = (const float*)d_in[1];
    const float* w    = (const float*)d_in[2];
    const float* b    = (const float*)d_in[3];
    const int*   row  = (const int*)d_in[4];
    const int*   col  = (const int*)d_in[5];
    float* out = (float*)d_out;

    const size_t tElems = (size_t)M_ * ROWB_;             // 6.4M bf16 per term
    const size_t tBytes = tElems * 2;                     // 12.8 MB
    const size_t csrBytes = (size_t)(M_ + 1) * 4 + (size_t)M_ * 4
                          + 2 * (size_t)NNZ_ * 8 + 4096;  // pairs + stage
    const size_t fusedBytes = 4 * tBytes + csrBytes;      // ~71 MB
    const bool fused = ws_size >= fusedBytes;

    unsigned short* X0 = (unsigned short*)d_ws;
    unsigned short* T1 = X0 + tElems;
    unsigned short* T2 = T1 + tElems;
    unsigned short* T3 = fused ? (T2 + tElems) : T1;      // fallback: in-place
    char* p = (char*)(fused ? (T3 + tElems) : (T2 + tElems));
    int2* pairs   = (int2*)p;              p += (size_t)NNZ_ * 8;
    int2* stage   = (int2*)p;              p += (size_t)NNZ_ * 8;
    int*  row_ptr = (int*)p;               p += (size_t)(M_ + 1) * 4;
    int*  cnt     = (int*)p;               p += (size_t)M_ * 4;
    int*  bsum    = (int*)p;               p += 1024;
    int*  boff    = (int*)p;               p += 1024;
    int*  bticket = (int*)p;

    const int TB = 256;
    dim3 blk(TB);
    dim3 gN((NNZ_ + TB - 1) / TB);                 // per-nnz
    dim3 gX((M_ * ROWB_ + TB - 1) / TB);           // build_x0
    dim3 gS((M_ + RPBLK_ - 1) / RPBLK_);           // spmm: 8 rows per block
    dim3 gFM(1024);                                // MFMA final: grid-stride waves
    dim3 gF((M_ * N_ + TB - 1) / TB);              // fallback k_accum

    // ---- build CSR row_ptr ----
    hipMemsetAsync(cnt, 0, (size_t)M_ * 4, stream);
    hipLaunchKernelGGL(k_hist,      gN, blk, 0, stream, row, cnt);
    hipLaunchKernelGGL(k_blocksum,  dim3(SCAN_NB), blk, 0, stream, cnt, bsum);
    hipLaunchKernelGGL(k_scan_bsum, dim3(1), blk, 0, stream, bsum, boff);
    hipLaunchKernelGGL(k_emit,      dim3(SCAN_NB), blk, 0, stream, cnt, boff, row_ptr);

    // ---- two-phase bucketed scatter ----
    hipLaunchKernelGGL(k_binit,    dim3(1), blk, 0, stream, row_ptr, bticket);
    hipLaunchKernelGGL(k_bscatter, dim3(BSC_BLOCKS_), blk, 0, stream,
                       vals, row, col, bticket, stage);
    hipLaunchKernelGGL(k_bsort,    dim3(NBKT_), blk, 0, stream, row_ptr, stage, pairs);

    // ---- X0 (bf16) ----
    hipLaunchKernelGGL(k_build_x0, gX, blk, 0, stream, x, X0);

    const long long* pr = (const long long*)pairs;
    if (fused) {
        hipLaunchKernelGGL(k_spmm_bf16, gS, blk, 0, stream, X0, (const unsigned short*)nullptr,
                           T1, row_ptr, pr, 1.0f);
        hipLaunchKernelGGL(k_spmm_bf16, gS, blk, 0, stream, T1, X0, T2, row_ptr, pr, 2.0f);
        hipLaunchKernelGGL(k_spmm_bf16, gS, blk, 0, stream, T2, T1, T3, row_ptr, pr, 2.0f);
        hipLaunchKernelGGL(k_final, gFM, blk, 0, stream, X0, T1, T2, T3, w, b, out);
    } else {
        hipLaunchKernelGGL(k_accum, gF, blk, 0, stream, X0, w, b, out, 0, 1);
        hipLaunchKernelGGL(k_spmm_bf16, gS, blk, 0, stream, X0, (const unsigned short*)nullptr,
                           T1, row_ptr, pr, 1.0f);
        hipLaunchKernelGGL(k_accum, gF, blk, 0, stream, T1, w, b, out, 1, 0);
        hipLaunchKernelGGL(k_spmm_bf16, gS, blk, 0, stream, T1, X0, T2, row_ptr, pr, 2.0f);
        hipLaunchKernelGGL(k_accum, gF, blk, 0, stream, T2, w, b, out, 2, 0);
        // T3 overwrites T1 in place: same-thread read-then-write, no hazard.
        hipLaunchKernelGGL(k_spmm_bf16, gS, blk, 0, stream, T2, T1, T1, row_ptr, pr, 2.0f);
        hipLaunchKernelGGL(k_accum, gF, blk, 0, stream, T1, w, b, out, 3, 0);
    }
}

// Round 16
// 204.368 us; speedup vs baseline: 4.3484x; 1.1078x over previous
//
#include <hip/hip_runtime.h>

// Problem constants (fixed-shape problem)
constexpr int N_    = 8;
constexpr int M_    = 50000;
constexpr int FIN_  = 16;
constexpr int FOUT_ = 32;
constexpr int KCH_  = 4;
constexpr int NNZ_  = 800000;
constexpr int ROWB_ = 128;                  // bf16 elems per term row (256 B)
constexpr int SCAN_NB = (M_ + 255) / 256;   // 196 scan blocks
constexpr int RPB16_ = 16;                  // rows per spmm block (256 thr / 16)
constexpr int NBKT_  = (M_ + 255) / 256;    // 196 row-buckets (256 rows each)
constexpr int BSC_BLOCKS_ = 256;            // bucket-scatter blocks
constexpr int CHUNK_ = NNZ_ / BSC_BLOCKS_;  // 3125 nnz per block (exact)
constexpr int NTILE_ = M_ / 2;              // 25000 2-m tiles (exact)

// Term-row internal layout: element c = n*16 + f  (m-row is 256 B contiguous;
// spmm gathers whole rows so the internal order is free — chosen so both the
// MFMA A-fragment and k_accum read contiguous 16 B per (m,n,k)).

typedef float f32x4 __attribute__((ext_vector_type(4)));
typedef unsigned short u16x8 __attribute__((ext_vector_type(8)));
typedef short bf16x8 __attribute__((ext_vector_type(8)));   // MFMA A/B fragment
typedef float f32x4v __attribute__((ext_vector_type(4)));   // MFMA C/D fragment

__device__ __forceinline__ float bf2f(unsigned short u) {
    return __uint_as_float(((unsigned int)u) << 16);
}
__device__ __forceinline__ unsigned short f2bf(float f) {   // RNE
    unsigned int u = __float_as_uint(f);
    return (unsigned short)((u + 0x7fffu + ((u >> 16) & 1u)) >> 16);
}

// ---------------------------------------------------------------------------
// zero helper (the runtime's fillBufferAligned ran at 8% occupancy, 40 µs!)
__global__ void k_zero(int4* __restrict__ p, int n4) {
    int i = blockIdx.x * blockDim.x + threadIdx.x;
    if (i < n4) p[i] = make_int4(0, 0, 0, 0);
}

// ---------------------------------------------------------------------------
// X0 bf16: X0[m][n*16+f] = x[n][m][f]  (consecutive t -> consecutive x: coalesced)
__global__ void k_build_x0(const float* __restrict__ x, unsigned short* __restrict__ t0) {
    int t = blockIdx.x * blockDim.x + threadIdx.x;
    if (t >= M_ * ROWB_) return;
    int f = t & 15;
    int n = (t >> 4) & 7;
    int m = t >> 7;
    t0[t] = f2bf(x[((size_t)n * M_ + m) * FIN_ + f]);
}

// ---------------------------------------------------------------------------
// CSR row_ptr build (hist + hierarchical scan)
__global__ void k_hist(const int* __restrict__ row, int* __restrict__ cnt) {
    int i = blockIdx.x * blockDim.x + threadIdx.x;
    if (i < NNZ_) atomicAdd(&cnt[row[i]], 1);
}

__global__ void k_blocksum(const int* __restrict__ cnt, int* __restrict__ bsum) {
    __shared__ int s[256];
    int t = threadIdx.x;
    int idx = blockIdx.x * 256 + t;
    s[t] = (idx < M_) ? cnt[idx] : 0;
    __syncthreads();
    for (int off = 128; off > 0; off >>= 1) {
        if (t < off) s[t] += s[t + off];
        __syncthreads();
    }
    if (t == 0) bsum[blockIdx.x] = s[0];
}

__global__ void k_scan_bsum(const int* __restrict__ bsum, int* __restrict__ boff) {
    __shared__ int s[256];
    int t = threadIdx.x;
    int v = (t < SCAN_NB) ? bsum[t] : 0;
    s[t] = v;
    __syncthreads();
    for (int off = 1; off < 256; off <<= 1) {
        int a = (t >= off) ? s[t - off] : 0;
        __syncthreads();
        s[t] += a;
        __syncthreads();
    }
    if (t < SCAN_NB) boff[t] = s[t] - v;   // exclusive
}

__global__ void k_emit(const int* __restrict__ cnt, const int* __restrict__ boff,
                       int* __restrict__ row_ptr) {
    __shared__ int s[256];
    int t = threadIdx.x;
    int idx = blockIdx.x * 256 + t;
    int v = (idx < M_) ? cnt[idx] : 0;
    s[t] = v;
    __syncthreads();
    for (int off = 1; off < 256; off <<= 1) {
        int a = (t >= off) ? s[t - off] : 0;
        __syncthreads();
        s[t] += a;
        __syncthreads();
    }
    if (idx < M_) row_ptr[idx] = boff[blockIdx.x] + s[t] - v;
    if (idx == 0) row_ptr[M_] = NNZ_;
}

// bticket[b] = row_ptr[b*256] (bucket staging base = its CSR region base)
__global__ void k_binit(const int* __restrict__ row_ptr, int* __restrict__ bticket) {
    int b = blockIdx.x * blockDim.x + threadIdx.x;
    if (b < NBKT_) bticket[b] = row_ptr[b * 256];
}

// ---------------------------------------------------------------------------
// Phase 1: bucket scatter (one global atomic per (block,bucket); sequential
// per-bucket writes -> full-line write utilization).
__global__ __launch_bounds__(256) void k_bscatter(
        const float* __restrict__ vals, const int* __restrict__ row,
        const int* __restrict__ col, int* __restrict__ bticket,
        int2* __restrict__ stage) {
    __shared__ int cnt[NBKT_];
    __shared__ int base[NBKT_];
    const int t = threadIdx.x;
    const int i0 = blockIdx.x * CHUNK_;
    for (int b = t; b < NBKT_; b += 256) cnt[b] = 0;
    __syncthreads();
    for (int i = i0 + t; i < i0 + CHUNK_; i += 256)
        atomicAdd(&cnt[row[i] >> 8], 1);
    __syncthreads();
    for (int b = t; b < NBKT_; b += 256) {
        base[b] = (cnt[b] > 0) ? atomicAdd(&bticket[b], cnt[b]) : 0;
        cnt[b] = 0;
    }
    __syncthreads();
    for (int i = i0 + t; i < i0 + CHUNK_; i += 256) {
        const int r = row[i];
        const int b = r >> 8;
        const int k = atomicAdd(&cnt[b], 1);
        stage[base[b] + k] = make_int2(__float_as_int(vals[i]),
                                       col[i] | ((r & 255) << 16));
    }
}

// Phase 2: bucket-local CSR ordering.
__global__ __launch_bounds__(256) void k_bsort(
        const int* __restrict__ row_ptr, const int2* __restrict__ stage,
        int2* __restrict__ pairs) {
    __shared__ int rp_loc[257];
    __shared__ int c2[256];
    const int b  = blockIdx.x;
    const int t  = threadIdx.x;
    const int r0 = b * 256;
    const int nr = (r0 + 256 <= M_) ? 256 : (M_ - r0);
    if (t < nr) rp_loc[t] = row_ptr[r0 + t];
    if (t == 0) rp_loc[nr] = row_ptr[r0 + nr];   // boundary: ALWAYS loaded
    c2[t] = 0;
    __syncthreads();
    const int base = rp_loc[0];
    const int end  = rp_loc[nr];
    for (int e = base + t; e < end; e += 256) {
        const int2 en = stage[e];
        const int rl = en.y >> 16;
        const int k  = atomicAdd(&c2[rl], 1);
        pairs[rp_loc[rl] + k] = make_int2(en.x, en.y & 0xFFFF);
    }
}

// ---------------------------------------------------------------------------
// bf16 SpMM: Y[r,:] = scale * sum_j v_j * X[c_j,:]  (- prev[r,:] if prev)
// 16 lanes per row (16 B ushort8 per lane): 4 rows/wave x 2-unroll = 8
// independent pair->gather chains per wave (2x the MLP of 32-lane version).
__global__ __launch_bounds__(256) void k_spmm_bf16(
        const unsigned short* __restrict__ X, const unsigned short* __restrict__ prev,
        unsigned short* __restrict__ Y, const int* __restrict__ rp,
        const long long* __restrict__ pairs, float scale) {
    const int r = blockIdx.x * RPB16_ + (threadIdx.x >> 4);
    if (r >= M_) return;
    const int lane = threadIdx.x & 15;
    const size_t off = (size_t)r * ROWB_ + lane * 8;

    const int jb = rp[r], je = rp[r + 1];
    f32x4 s0lo = {0.f,0.f,0.f,0.f}, s0hi = {0.f,0.f,0.f,0.f};
    f32x4 s1lo = {0.f,0.f,0.f,0.f}, s1hi = {0.f,0.f,0.f,0.f};
    int j = jb;
    for (; j + 1 < je; j += 2) {
        const long long p0 = pairs[j], p1 = pairs[j + 1];
        const float v0 = __int_as_float((int)p0);
        const float v1 = __int_as_float((int)p1);
        const int   c0 = (int)(p0 >> 32), c1 = (int)(p1 >> 32);
        const u16x8 u0 = *reinterpret_cast<const u16x8*>(X + (size_t)c0 * ROWB_ + lane * 8);
        const u16x8 u1 = *reinterpret_cast<const u16x8*>(X + (size_t)c1 * ROWB_ + lane * 8);
        const f32x4 x0lo = {bf2f(u0[0]), bf2f(u0[1]), bf2f(u0[2]), bf2f(u0[3])};
        const f32x4 x0hi = {bf2f(u0[4]), bf2f(u0[5]), bf2f(u0[6]), bf2f(u0[7])};
        const f32x4 x1lo = {bf2f(u1[0]), bf2f(u1[1]), bf2f(u1[2]), bf2f(u1[3])};
        const f32x4 x1hi = {bf2f(u1[4]), bf2f(u1[5]), bf2f(u1[6]), bf2f(u1[7])};
        s0lo += v0 * x0lo; s0hi += v0 * x0hi;
        s1lo += v1 * x1lo; s1hi += v1 * x1hi;
    }
    if (j < je) {
        const long long p0 = pairs[j];
        const float v0 = __int_as_float((int)p0);
        const int   c0 = (int)(p0 >> 32);
        const u16x8 u0 = *reinterpret_cast<const u16x8*>(X + (size_t)c0 * ROWB_ + lane * 8);
        const f32x4 x0lo = {bf2f(u0[0]), bf2f(u0[1]), bf2f(u0[2]), bf2f(u0[3])};
        const f32x4 x0hi = {bf2f(u0[4]), bf2f(u0[5]), bf2f(u0[6]), bf2f(u0[7])};
        s0lo += v0 * x0lo; s0hi += v0 * x0hi;
    }
    f32x4 rlo = scale * (s0lo + s1lo);
    f32x4 rhi = scale * (s0hi + s1hi);
    if (prev) {
        const u16x8 pv = *reinterpret_cast<const u16x8*>(prev + off);
        rlo -= (f32x4){bf2f(pv[0]), bf2f(pv[1]), bf2f(pv[2]), bf2f(pv[3])};
        rhi -= (f32x4){bf2f(pv[4]), bf2f(pv[5]), bf2f(pv[6]), bf2f(pv[7])};
    }
    u16x8 o;
    o[0] = f2bf(rlo.x); o[1] = f2bf(rlo.y); o[2] = f2bf(rlo.z); o[3] = f2bf(rlo.w);
    o[4] = f2bf(rhi.x); o[5] = f2bf(rhi.y); o[6] = f2bf(rhi.z); o[7] = f2bf(rhi.w);
    *reinterpret_cast<u16x8*>(Y + off) = o;
}

// ---------------------------------------------------------------------------
// MFMA final einsum. Per 2-m tile: out[16 rows = 2m x 8n][32 o] =
//   sum_{K=64 (f,kcheb)} A[row][K] * B[K][o] + bias,
// as 2 chained mfma_f32_16x16x32_bf16 per o-half (K split 0..31 -> T0/T1,
// 32..63 -> T2/T3). A-frag: lane l&15 = row (mloc = (l&15)>>3, n = l&7),
// K-group (l>>4)*8+j -> one contiguous 16 B term load. B-frag: w bf16 held in
// 16 VGPRs for the whole kernel (consistent K labels A<->B make the result
// invariant to the HW's internal K permutation). C/D: col=l&15,
// row=(l>>4)*4+reg [verified mapping]. Bias folded into acc init. No LDS.
__global__ __launch_bounds__(256) void k_final(
        const unsigned short* __restrict__ T0, const unsigned short* __restrict__ T1,
        const unsigned short* __restrict__ T2, const unsigned short* __restrict__ T3,
        const float* __restrict__ w, const float* __restrict__ b,
        float* __restrict__ out) {
    const int lane = threadIdx.x & 63;
    const int lg   = lane >> 4;          // 0..3 (K-group / D-row group)
    const int ll   = lane & 15;          // A row / B col / D col
    const int wid    = (blockIdx.x * blockDim.x + threadIdx.x) >> 6;
    const int nwaves = (gridDim.x * blockDim.x) >> 6;

    // B fragments: mm = which MFMA (0: kcheb 0/1, 1: kcheb 2/3), oh = o-half.
    bf16x8 bfrag[2][2];
#pragma unroll
    for (int mm = 0; mm < 2; ++mm)
#pragma unroll
        for (int oh = 0; oh < 2; ++oh)
#pragma unroll
            for (int j = 0; j < 8; ++j) {
                const int k  = lg * 8 + j;            // 0..31
                const int kc = mm * 2 + (k >> 4);     // cheb index
                const int f  = k & 15;
                bfrag[mm][oh][j] =
                    (short)f2bf(w[(f * KCH_ + kc) * FOUT_ + oh * 16 + ll]);
            }
    const float bias0 = b[ll], bias1 = b[16 + ll];

    // A-source: MFMA0 reads T0 (lg 0,1) / T1 (lg 2,3); MFMA1 reads T2/T3.
    const unsigned short* TA = (lg < 2) ? T0 : T1;
    const unsigned short* TB = (lg < 2) ? T2 : T3;
    const int mloc = ll >> 3;
    const int n    = ll & 7;
    const int fofs = (lg & 1) * 8;
    const size_t eoff = (size_t)n * 16 + fofs;

    for (int tile = wid; tile < NTILE_; tile += nwaves) {
        const int m0 = tile * 2;
        const size_t rowoff = (size_t)(m0 + mloc) * ROWB_ + eoff;
        const bf16x8 a01 = *reinterpret_cast<const bf16x8*>(TA + rowoff);
        const bf16x8 a23 = *reinterpret_cast<const bf16x8*>(TB + rowoff);

        f32x4v acc0 = {bias0, bias0, bias0, bias0};
        f32x4v acc1 = {bias1, bias1, bias1, bias1};
        acc0 = __builtin_amdgcn_mfma_f32_16x16x32_bf16(a01, bfrag[0][0], acc0, 0, 0, 0);
        acc0 = __builtin_amdgcn_mfma_f32_16x16x32_bf16(a23, bfrag[1][0], acc0, 0, 0, 0);
        acc1 = __builtin_amdgcn_mfma_f32_16x16x32_bf16(a01, bfrag[0][1], acc1, 0, 0, 0);
        acc1 = __builtin_amdgcn_mfma_f32_16x16x32_bf16(a23, bfrag[1][1], acc1, 0, 0, 0);

#pragma unroll
        for (int r = 0; r < 4; ++r) {
            const int drow = lg * 4 + r;              // 0..15
            const int dm   = drow >> 3;
            const int dn   = drow & 7;
            float* base = out + ((size_t)dn * M_ + m0 + dm) * FOUT_;
            base[ll]      = acc0[r];
            base[16 + ll] = acc1[r];
        }
    }
}

// ---------------------------------------------------------------------------
// fallback per-term accumulation (bf16 term, [m][n*16+f] layout)
__global__ __launch_bounds__(256) void k_accum(
        const unsigned short* __restrict__ T, const float* __restrict__ w,
        const float* __restrict__ b, float* __restrict__ out, int k, int init) {
    int t = blockIdx.x * blockDim.x + threadIdx.x;
    if (t >= M_ * N_) return;
    const int n = t & 7;
    const int m = t >> 3;

    float* base = out + ((size_t)n * M_ + m) * FOUT_;
    float4 acc[8];
#pragma unroll
    for (int o4 = 0; o4 < 8; ++o4)
        acc[o4] = init ? *reinterpret_cast<const float4*>(b + o4 * 4)
                       : *reinterpret_cast<const float4*>(base + o4 * 4);

    const unsigned short* tk = T + (size_t)m * ROWB_ + n * 16;
    const u16x8 lo = *reinterpret_cast<const u16x8*>(tk);
    const u16x8 hi = *reinterpret_cast<const u16x8*>(tk + 8);
#pragma unroll
    for (int f = 0; f < FIN_; ++f) {
        const float tv = bf2f(f < 8 ? lo[f] : hi[f - 8]);
        const float* wr = w + (f * KCH_ + k) * FOUT_;
#pragma unroll
        for (int o4 = 0; o4 < 8; ++o4) {
            float4 wv = *reinterpret_cast<const float4*>(wr + o4 * 4);
            acc[o4].x += tv * wv.x; acc[o4].y += tv * wv.y;
            acc[o4].z += tv * wv.z; acc[o4].w += tv * wv.w;
        }
    }
#pragma unroll
    for (int o4 = 0; o4 < 8; ++o4)
        *reinterpret_cast<float4*>(base + o4 * 4) = acc[o4];
}

// ---------------------------------------------------------------------------
extern "C" void kernel_launch(void* const* d_in, const int* in_sizes, int n_in,
                              void* d_out, int out_size, void* d_ws, size_t ws_size,
                              hipStream_t stream) {
    const float* x    = (const float*)d_in[0];
    const float* vals = (const float*)d_in[1];
    const float* w    = (const float*)d_in[2];
    const float* b    = (const float*)d_in[3];
    const int*   row  = (const int*)d_in[4];
    const int*   col  = (const int*)d_in[5];
    float* out = (float*)d_out;

    const size_t tElems = (size_t)M_ * ROWB_;             // 6.4M bf16 per term
    const size_t tBytes = tElems * 2;                     // 12.8 MB
    const size_t csrBytes = (size_t)(M_ + 1) * 4 + (size_t)M_ * 4
                          + 2 * (size_t)NNZ_ * 8 + 4096;  // pairs + stage
    const size_t fusedBytes = 4 * tBytes + csrBytes;      // ~71 MB
    const bool fused = ws_size >= fusedBytes;

    unsigned short* X0 = (unsigned short*)d_ws;
    unsigned short* T1 = X0 + tElems;
    unsigned short* T2 = T1 + tElems;
    unsigned short* T3 = fused ? (T2 + tElems) : T1;      // fallback: in-place
    char* p = (char*)(fused ? (T3 + tElems) : (T2 + tElems));
    int2* pairs   = (int2*)p;              p += (size_t)NNZ_ * 8;
    int2* stage   = (int2*)p;              p += (size_t)NNZ_ * 8;
    int*  row_ptr = (int*)p;               p += (size_t)(M_ + 1) * 4;
    int*  cnt     = (int*)p;               p += (size_t)M_ * 4;
    int*  bsum    = (int*)p;               p += 1024;
    int*  boff    = (int*)p;               p += 1024;
    int*  bticket = (int*)p;

    const int TB = 256;
    dim3 blk(TB);
    dim3 gN((NNZ_ + TB - 1) / TB);                 // per-nnz
    dim3 gX((M_ * ROWB_ + TB - 1) / TB);           // build_x0
    dim3 gS((M_ + RPB16_ - 1) / RPB16_);           // spmm: 16 rows per block
    dim3 gFM(1024);                                // MFMA final: grid-stride waves
    dim3 gF((M_ * N_ + TB - 1) / TB);              // fallback k_accum
    dim3 gZ((M_ / 4 + TB - 1) / TB);               // k_zero (M_ % 4 == 0)

    // ---- build CSR row_ptr ----
    hipLaunchKernelGGL(k_zero,      gZ, blk, 0, stream, (int4*)cnt, M_ / 4);
    hipLaunchKernelGGL(k_hist,      gN, blk, 0, stream, row, cnt);
    hipLaunchKernelGGL(k_blocksum,  dim3(SCAN_NB), blk, 0, stream, cnt, bsum);
    hipLaunchKernelGGL(k_scan_bsum, dim3(1), blk, 0, stream, bsum, boff);
    hipLaunchKernelGGL(k_emit,      dim3(SCAN_NB), blk, 0, stream, cnt, boff, row_ptr);

    // ---- two-phase bucketed scatter ----
    hipLaunchKernelGGL(k_binit,    dim3(1), blk, 0, stream, row_ptr, bticket);
    hipLaunchKernelGGL(k_bscatter, dim3(BSC_BLOCKS_), blk, 0, stream,
                       vals, row, col, bticket, stage);
    hipLaunchKernelGGL(k_bsort,    dim3(NBKT_), blk, 0, stream, row_ptr, stage, pairs);

    // ---- X0 (bf16) ----
    hipLaunchKernelGGL(k_build_x0, gX, blk, 0, stream, x, X0);

    const long long* pr = (const long long*)pairs;
    if (fused) {
        hipLaunchKernelGGL(k_spmm_bf16, gS, blk, 0, stream, X0, (const unsigned short*)nullptr,
                           T1, row_ptr, pr, 1.0f);
        hipLaunchKernelGGL(k_spmm_bf16, gS, blk, 0, stream, T1, X0, T2, row_ptr, pr, 2.0f);
        hipLaunchKernelGGL(k_spmm_bf16, gS, blk, 0, stream, T2, T1, T3, row_ptr, pr, 2.0f);
        hipLaunchKernelGGL(k_final, gFM, blk, 0, stream, X0, T1, T2, T3, w, b, out);
    } else {
        hipLaunchKernelGGL(k_accum, gF, blk, 0, stream, X0, w, b, out, 0, 1);
        hipLaunchKernelGGL(k_spmm_bf16, gS, blk, 0, stream, X0, (const unsigned short*)nullptr,
                           T1, row_ptr, pr, 1.0f);
        hipLaunchKernelGGL(k_accum, gF, blk, 0, stream, T1, w, b, out, 1, 0);
        hipLaunchKernelGGL(k_spmm_bf16, gS, blk, 0, stream, T1, X0, T2, row_ptr, pr, 2.0f);
        hipLaunchKernelGGL(k_accum, gF, blk, 0, stream, T2, w, b, out, 2, 0);
        // T3 overwrites T1 in place: same-thread read-then-write, no hazard.
        hipLaunchKernelGGL(k_spmm_bf16, gS, blk, 0, stream, T2, T1, T1, row_ptr, pr, 2.0f);
        hipLaunchKernelGGL(k_accum, gF, blk, 0, stream, T1, w, b, out, 3, 0);
    }
}